// Round 7
// baseline (1920.386 us; speedup 1.0000x reference)
//
#include <hip/hip_runtime.h>
#include <stdint.h>

// ---------------------------------------------------------------------------
// TransformerBlock B=32, L=512, D=256, H=4 — fp32 vector pipeline.
// Inputs fp32 (dict order, confirmed r2-r6); OUTPUT FP32 (reference dtype —
// the r0-r6 "bf16 output" assumption was traceback-context misreading).
// Keeps dtype/order autodetection as zero-risk insurance.
// ---------------------------------------------------------------------------
#define SEQ   512
#define DM    256
#define NB    32
#define NH    4
#define HD    (NH * DM)           // 1024
#define NEGV  (-4294967295.0f)

__device__ __forceinline__ float b2f(unsigned short u) {
    return __uint_as_float(((uint32_t)u) << 16);
}

// ---------------------------------------------------------------------------
// Detect input float dtype from a float tensor (Q). fp32: low ushorts are
// mantissa junk (~44% have bf16-exponent >= 144). bf16 N(0,1): never.
// ---------------------------------------------------------------------------
__global__ void detect_dtype(const unsigned short* __restrict__ q, int* __restrict__ flag)
{
    __shared__ int cnt;
    if (threadIdx.x == 0) cnt = 0;
    __syncthreads();
    if (threadIdx.x < 128) {
        unsigned short u = q[threadIdx.x * 2];
        int e = (u >> 7) & 0xFF;
        if (e >= 144) atomicAdd(&cnt, 1);
    }
    __syncthreads();
    if (threadIdx.x == 0) *flag = (cnt >= 4) ? 1 : 0;
}

__global__ __launch_bounds__(256) void convertf(
    const void* __restrict__ in, float* __restrict__ out, int n,
    const int* __restrict__ flag)
{
    int i = blockIdx.x * 256 + threadIdx.x;
    if (i >= n) return;
    if (*flag) out[i] = ((const float*)in)[i];
    else       out[i] = b2f(((const unsigned short*)in)[i]);
}

// ---------------------------------------------------------------------------
// Canonicalize mask to int32, auto-detecting uint8 / int32 / int64 encoding.
// ---------------------------------------------------------------------------
__global__ __launch_bounds__(256) void mask_canon(
    const unsigned char* __restrict__ raw, int* __restrict__ canon)
{
    __shared__ int enc_byte, enc_odd;
    int tid = threadIdx.x;
    if (tid == 0) { enc_byte = 0; enc_odd = 0; }
    __syncthreads();
    if (tid < 255 && raw[tid * 4 + 1]) atomicOr(&enc_byte, 1);
    if (tid < 128 && ((const int*)raw)[tid * 2 + 1]) atomicOr(&enc_odd, 1);
    __syncthreads();
    int i = blockIdx.x * 256 + tid;
    int v;
    if (enc_byte)      v = (raw[i] != 0);
    else if (enc_odd)  v = (((const int*)raw)[i] != 0);
    else               v = ((((const int*)raw)[i * 2] | ((const int*)raw)[i * 2 + 1]) != 0);
    canon[i] = v;
}

// ---------------------------------------------------------------------------
// fp32 transpose, batched: out[c][r] = in[r][c]; 32x32 LDS tiles.
// ---------------------------------------------------------------------------
__global__ __launch_bounds__(256) void transpose_f32(
    const float* __restrict__ in, float* __restrict__ out,
    int ldin, int ldout, long sInB, long sInH, long sOutB, long sOutH, int Hdiv)
{
    int z = blockIdx.z; int b = z / Hdiv; int h = z % Hdiv;
    const float* ip = in + b * sInB + h * sInH;
    float* op = out + b * sOutB + h * sOutH;
    __shared__ float tile[32][33];
    int r0 = blockIdx.y * 32, c0 = blockIdx.x * 32;
    int i = threadIdx.x >> 3;
    int j = (threadIdx.x & 7) * 4;
    float4 v = *reinterpret_cast<const float4*>(ip + (long)(r0 + i) * ldin + c0 + j);
    tile[i][j + 0] = v.x; tile[i][j + 1] = v.y; tile[i][j + 2] = v.z; tile[i][j + 3] = v.w;
    __syncthreads();
    float4 w;
    w.x = tile[j + 0][i]; w.y = tile[j + 1][i]; w.z = tile[j + 2][i]; w.w = tile[j + 3][i];
    *reinterpret_cast<float4*>(op + (long)(c0 + i) * ldout + r0 + j) = w;
}

// ---------------------------------------------------------------------------
// Vector fp32 GEMM: C[m][n] = scale * sum_k A[m][k]*Bt[n][k] (+bias)(relu)
// 64x64 tile/block (256 thr, 4x4/thread), K-tiles of 16, LDS-staged.
// PE: add pe[(m&511)*256+k] to A while staging. Batched via blockIdx.z.
// ---------------------------------------------------------------------------
template<bool PE, bool BIAS, bool RELU>
__global__ __launch_bounds__(256) void vgemm(
    const float* __restrict__ A, int lda,
    const float* __restrict__ B, int ldb,
    float* __restrict__ C, int ldc,
    const float* __restrict__ bias, const float* __restrict__ pe,
    float scale, int K, int Hdiv,
    long sAb, long sAh, long sAz,
    long sBb, long sBh, long sBz,
    long sCb, long sCh, long sCz)
{
    int z  = blockIdx.z;
    int bb = z / Hdiv, hh = z % Hdiv;
    const float* Ab = A + bb * sAb + hh * sAh + (long)z * sAz;
    const float* Bb = B + bb * sBb + hh * sBh + (long)z * sBz;
    float*       Cb = C + bb * sCb + hh * sCh + (long)z * sCz;

    const int m0 = blockIdx.y * 64;
    const int n0 = blockIdx.x * 64;

    __shared__ float As[64][17];
    __shared__ float Bs[64][17];

    const int tid = threadIdx.x;
    const int tx  = tid & 15;
    const int ty  = tid >> 4;
    const int lr  = tid >> 2;
    const int lc  = (tid & 3) * 4;

    float acc[4][4] = {};

    for (int k0 = 0; k0 < K; k0 += 16) {
        float4 av = *reinterpret_cast<const float4*>(Ab + (long)(m0 + lr) * lda + k0 + lc);
        if (PE) {
            const float* pr = pe + (long)((m0 + lr) & (SEQ - 1)) * DM + k0 + lc;
            av.x += pr[0]; av.y += pr[1]; av.z += pr[2]; av.w += pr[3];
        }
        float4 bv = *reinterpret_cast<const float4*>(Bb + (long)(n0 + lr) * ldb + k0 + lc);
        As[lr][lc + 0] = av.x; As[lr][lc + 1] = av.y;
        As[lr][lc + 2] = av.z; As[lr][lc + 3] = av.w;
        Bs[lr][lc + 0] = bv.x; Bs[lr][lc + 1] = bv.y;
        Bs[lr][lc + 2] = bv.z; Bs[lr][lc + 3] = bv.w;
        __syncthreads();
#pragma unroll
        for (int kk = 0; kk < 16; ++kk) {
            float a[4], b[4];
#pragma unroll
            for (int i = 0; i < 4; ++i) a[i] = As[ty * 4 + i][kk];
#pragma unroll
            for (int j = 0; j < 4; ++j) b[j] = Bs[tx * 4 + j][kk];
#pragma unroll
            for (int i = 0; i < 4; ++i)
#pragma unroll
                for (int j = 0; j < 4; ++j) acc[i][j] += a[i] * b[j];
        }
        __syncthreads();
    }

#pragma unroll
    for (int i = 0; i < 4; ++i) {
        int row = m0 + ty * 4 + i;
#pragma unroll
        for (int j = 0; j < 4; ++j) {
            int col = n0 + tx * 4 + j;
            float v = acc[i][j] * scale;
            if (BIAS) v += bias[col];
            if (RELU) v = fmaxf(v, 0.f);
            Cb[(long)row * ldc + col] = v;
        }
    }
}

// ---------------------------------------------------------------------------
// Masked softmax over 512-wide fp32 rows, fp32 P in place.
// full_mask[q][k] = (k > q) || mask[b][q]; b from GLOBAL bh0+z.
// ---------------------------------------------------------------------------
__global__ __launch_bounds__(256) void softmax_f32(
    float* __restrict__ S, const int* __restrict__ mask, int bh0)
{
    int row  = blockIdx.x * 4 + (threadIdx.x >> 6);
    int lane = threadIdx.x & 63;
    int z = row >> 9;
    int q = row & (SEQ - 1);
    int b = (bh0 + z) >> 2;
    bool rowmask = mask[b * SEQ + q] != 0;
    float* Srow = S + (long)row * SEQ;
    float4* S4 = reinterpret_cast<float4*>(Srow);

    float4 v0 = S4[lane];
    float4 v1 = S4[64 + lane];
    float vals[8] = {v0.x, v0.y, v0.z, v0.w, v1.x, v1.y, v1.z, v1.w};
    int k0 = lane * 4;
#pragma unroll
    for (int t = 0; t < 8; ++t) {
        int k = (t < 4) ? (k0 + t) : (256 + k0 + (t - 4));
        if (k > q || rowmask) vals[t] = NEGV;
    }
    float mx = vals[0];
#pragma unroll
    for (int t = 1; t < 8; ++t) mx = fmaxf(mx, vals[t]);
#pragma unroll
    for (int off = 32; off > 0; off >>= 1) mx = fmaxf(mx, __shfl_xor(mx, off));
    float sum = 0.f;
#pragma unroll
    for (int t = 0; t < 8; ++t) { vals[t] = __expf(vals[t] - mx); sum += vals[t]; }
#pragma unroll
    for (int off = 32; off > 0; off >>= 1) sum += __shfl_xor(sum, off);
    float inv = 1.0f / sum;

    S4[lane]      = make_float4(vals[0] * inv, vals[1] * inv, vals[2] * inv, vals[3] * inv);
    S4[64 + lane] = make_float4(vals[4] * inv, vals[5] * inv, vals[6] * inv, vals[7] * inv);
}

// ---------------------------------------------------------------------------
// LN1: x = AttO + Qc + pe  ->  fp32 X
// ---------------------------------------------------------------------------
__global__ __launch_bounds__(256) void ln1_kernel(
    const float* __restrict__ AttO, const float* __restrict__ Qc,
    const float* __restrict__ pe,
    const float* __restrict__ gamma, const float* __restrict__ beta,
    float* __restrict__ out)
{
    int row  = blockIdx.x * 4 + (threadIdx.x >> 6);
    int lane = threadIdx.x & 63;
    long base = (long)row * DM + lane * 4;
    long pb   = (long)(row & (SEQ - 1)) * DM + lane * 4;
    float4 a = *reinterpret_cast<const float4*>(AttO + base);
    float4 qv = *reinterpret_cast<const float4*>(Qc + base);
    float4 pv = *reinterpret_cast<const float4*>(pe + pb);
    float x[4] = {a.x + qv.x + pv.x, a.y + qv.y + pv.y,
                  a.z + qv.z + pv.z, a.w + qv.w + pv.w};
    float s = x[0] + x[1] + x[2] + x[3];
#pragma unroll
    for (int off = 32; off > 0; off >>= 1) s += __shfl_xor(s, off);
    float mu = s * (1.0f / DM);
    float vs = 0.f;
#pragma unroll
    for (int t = 0; t < 4; ++t) { float d = x[t] - mu; vs += d * d; }
#pragma unroll
    for (int off = 32; off > 0; off >>= 1) vs += __shfl_xor(vs, off);
    float inv = rsqrtf(vs * (1.0f / DM) + 1e-5f);
    int d0 = lane * 4;
    float4 g = *reinterpret_cast<const float4*>(gamma + d0);
    float4 bt = *reinterpret_cast<const float4*>(beta + d0);
    float4 o;
    o.x = (x[0] - mu) * inv * g.x + bt.x;
    o.y = (x[1] - mu) * inv * g.y + bt.y;
    o.z = (x[2] - mu) * inv * g.z + bt.z;
    o.w = (x[3] - mu) * inv * g.w + bt.w;
    *reinterpret_cast<float4*>(out + base) = o;
}

// ---------------------------------------------------------------------------
// LN2: x = F + X  ->  FP32 out (reference output dtype)
// ---------------------------------------------------------------------------
__global__ __launch_bounds__(256) void ln2_kernel(
    const float* __restrict__ F, const float* __restrict__ X,
    const float* __restrict__ gamma, const float* __restrict__ beta,
    float* __restrict__ out)
{
    int row  = blockIdx.x * 4 + (threadIdx.x >> 6);
    int lane = threadIdx.x & 63;
    long base = (long)row * DM + lane * 4;
    float4 a = *reinterpret_cast<const float4*>(F + base);
    float4 c = *reinterpret_cast<const float4*>(X + base);
    float x[4] = {a.x + c.x, a.y + c.y, a.z + c.z, a.w + c.w};
    float s = x[0] + x[1] + x[2] + x[3];
#pragma unroll
    for (int off = 32; off > 0; off >>= 1) s += __shfl_xor(s, off);
    float mu = s * (1.0f / DM);
    float vs = 0.f;
#pragma unroll
    for (int t = 0; t < 4; ++t) { float d = x[t] - mu; vs += d * d; }
#pragma unroll
    for (int off = 32; off > 0; off >>= 1) vs += __shfl_xor(vs, off);
    float inv = rsqrtf(vs * (1.0f / DM) + 1e-5f);
    int d0 = lane * 4;
    float4 g = *reinterpret_cast<const float4*>(gamma + d0);
    float4 bt = *reinterpret_cast<const float4*>(beta + d0);
    float4 o;
    o.x = (x[0] - mu) * inv * g.x + bt.x;
    o.y = (x[1] - mu) * inv * g.y + bt.y;
    o.z = (x[2] - mu) * inv * g.z + bt.z;
    o.w = (x[3] - mu) * inv * g.w + bt.w;
    *reinterpret_cast<float4*>(out + base) = o;
}

// ---------------------------------------------------------------------------
extern "C" void kernel_launch(void* const* d_in, const int* in_sizes, int n_in,
                              void* d_out, int out_size, void* d_ws, size_t ws_size,
                              hipStream_t stream)
{
    // input index mapping: dict order (confirmed via in_sizes[3]==16384 in r6);
    // sorted-key fallback kept as insurance.
    int iQ=0,iK=1,iV=2,iM=3,iPE=4,iWq=5,iWk=6,iWv=7,iWo=8,iw1=9,ib1=10,iw2=11,ib2=12,iG=13,iB=14;
    if (n_in >= 15 && in_sizes[3] == DM * HD) {
        iK=0; iQ=1; iV=2; iWk=3; iWo=4; iWq=5; iWv=6;
        ib1=7; ib2=8; iB=9; iG=10; iM=11; iPE=12; iw1=13; iw2=14;
    }

    const unsigned char* mask_raw = (const unsigned char*)d_in[iM];
    float* out = (float*)d_out;

    const size_t MiB = 1048576;
    char* ws = (char*)d_ws;

    int*   flag  = (int*)(ws);
    int*   maskc = (int*)(ws + 65536);
    float* Qc    = (float*)(ws + 1 * MiB);           // 16 MiB
    float* Kc    = (float*)(ws + 17 * MiB);          // 16 MiB
    float* Vc    = (float*)(ws + 33 * MiB);          // 16 MiB
    float* pec   = (float*)(ws + 49 * MiB);          // 800 KiB
    float* Wqc   = (float*)(ws + 50 * MiB);          // 1 MiB each
    float* Wkc   = (float*)(ws + 51 * MiB);
    float* Wvc   = (float*)(ws + 52 * MiB);
    float* Woc   = (float*)(ws + 53 * MiB);
    float* w1c   = (float*)(ws + 54 * MiB);
    float* w2c   = (float*)(ws + 54 * MiB + 262144);
    float* b1c   = (float*)(ws + 54 * MiB + 524288);
    float* b2c   = (float*)(ws + 54 * MiB + 528384);
    float* gc    = (float*)(ws + 54 * MiB + 532480);
    float* bc    = (float*)(ws + 54 * MiB + 536576);
    float* WqT   = (float*)(ws + 55 * MiB);          // 1 MiB each
    float* WkT   = (float*)(ws + 56 * MiB);
    float* WvT   = (float*)(ws + 57 * MiB);
    float* WoT   = (float*)(ws + 58 * MiB);
    float* AttO  = (float*)(ws + 59 * MiB);          // 16 MiB
    float* Xf    = (float*)(ws + 75 * MiB);          // 16 MiB
    char*  scr   = ws + 91 * MiB;

    int CB = 1;
    for (int cb = 8; cb >= 1; cb >>= 1) {
        size_t s = (size_t)(14 * cb) * MiB; if (s < 32 * MiB) s = 32 * MiB;
        if (91 * MiB + s <= ws_size) { CB = cb; break; }
    }
    const int NCH = NB / CB;
    const long CROWS = (long)CB * SEQ;

    float* Qh   = (float*)(scr);
    float* Kh   = (float*)(scr + (size_t)(2 * CB) * MiB);
    float* Vh   = (float*)(scr + (size_t)(4 * CB) * MiB);
    float* VhT  = (float*)(scr + (size_t)(6 * CB) * MiB);
    float* Vatt = (float*)(scr + (size_t)(8 * CB) * MiB);
    float* S    = (float*)(scr + (size_t)(10 * CB) * MiB);
    float* H1   = (float*)(scr);
    float* Ff   = (float*)(scr + 16 * MiB);

    const float scale = (float)(1.0 / (16.0 + 1e-6));

    // 0. dtype detect + canonicalize all float inputs to fp32
    detect_dtype<<<1, 128, 0, stream>>>((const unsigned short*)d_in[iQ], flag);
    struct CV { const void* in; float* out; int n; };
    const CV cvs[14] = {
        {d_in[iQ],  Qc,  NB * SEQ * DM}, {d_in[iK],  Kc,  NB * SEQ * DM},
        {d_in[iV],  Vc,  NB * SEQ * DM}, {d_in[iPE], pec, 800 * DM},
        {d_in[iWq], Wqc, DM * HD},       {d_in[iWk], Wkc, DM * HD},
        {d_in[iWv], Wvc, DM * HD},       {d_in[iWo], Woc, HD * DM},
        {d_in[iw1], w1c, DM * DM},       {d_in[iw2], w2c, DM * DM},
        {d_in[ib1], b1c, DM},            {d_in[ib2], b2c, DM},
        {d_in[iG],  gc,  DM},            {d_in[iB],  bc,  DM},
    };
    for (int i = 0; i < 14; ++i)
        convertf<<<(cvs[i].n + 255) / 256, 256, 0, stream>>>(cvs[i].in, cvs[i].out, cvs[i].n, flag);
    mask_canon<<<64, 256, 0, stream>>>(mask_raw, maskc);

    // 1. weight transposes -> (N x K) for the Bt GEMM
    transpose_f32<<<dim3(32, 8, 1), 256, 0, stream>>>(Wqc, WqT, HD, DM, 0, 0, 0, 0, 1);
    transpose_f32<<<dim3(32, 8, 1), 256, 0, stream>>>(Wkc, WkT, HD, DM, 0, 0, 0, 0, 1);
    transpose_f32<<<dim3(32, 8, 1), 256, 0, stream>>>(Wvc, WvT, HD, DM, 0, 0, 0, 0, 1);
    transpose_f32<<<dim3(8, 32, 1), 256, 0, stream>>>(Woc, WoT, DM, HD, 0, 0, 0, 0, 1);

    // 2. attention in NCH chunks of CB batches
    for (int c = 0; c < NCH; ++c) {
        const long r0  = (long)c * CROWS;
        const int  bh0 = c * CB * NH;
        const int  gy  = (int)(CROWS / 64);

        vgemm<true, false, false><<<dim3(16, gy, 1), 256, 0, stream>>>(
            Qc + r0 * DM, DM, WqT, DM, Qh, HD, nullptr, pec, 1.f, DM, 1,
            0,0,0, 0,0,0, 0,0,0);
        vgemm<true, false, false><<<dim3(16, gy, 1), 256, 0, stream>>>(
            Kc + r0 * DM, DM, WkT, DM, Kh, HD, nullptr, pec, 1.f, DM, 1,
            0,0,0, 0,0,0, 0,0,0);
        vgemm<true, false, false><<<dim3(16, gy, 1), 256, 0, stream>>>(
            Vc + r0 * DM, DM, WvT, DM, Vh, HD, nullptr, pec, 1.f, DM, 1,
            0,0,0, 0,0,0, 0,0,0);

        transpose_f32<<<dim3(8, 16, CB * NH), 256, 0, stream>>>(
            Vh, VhT, HD, SEQ, (long)SEQ * HD, DM, (long)SEQ * HD, (long)SEQ * DM, NH);

        vgemm<false, false, false><<<dim3(8, 8, CB * NH), 256, 0, stream>>>(
            Qh, HD, Kh, HD, S, SEQ, nullptr, nullptr, scale, DM, NH,
            (long)SEQ * HD, DM, 0, (long)SEQ * HD, DM, 0, 0, 0, (long)SEQ * SEQ);

        softmax_f32<<<512 * CB, 256, 0, stream>>>(S, maskc, bh0);

        vgemm<false, false, false><<<dim3(4, 8, CB * NH), 256, 0, stream>>>(
            S, SEQ, VhT, SEQ, Vatt, HD, nullptr, nullptr, 1.f, SEQ, NH,
            0, 0, (long)SEQ * SEQ, (long)SEQ * HD, (long)SEQ * DM, 0,
            (long)SEQ * HD, DM, 0);

        vgemm<false, false, false><<<dim3(4, gy, 1), 256, 0, stream>>>(
            Vatt, HD, WoT, HD, AttO + r0 * DM, DM, nullptr, nullptr, 1.f, HD, 1,
            0,0,0, 0,0,0, 0,0,0);
    }

    // 3. LN1: X = LN(Qc + pe + AttO)
    ln1_kernel<<<4096, 256, 0, stream>>>(AttO, Qc, pec, gc, bc, Xf);

    // 4. FFN1: H1 = relu(X @ w1^T + b1)
    vgemm<false, true, true><<<dim3(4, 256, 1), 256, 0, stream>>>(
        Xf, DM, w1c, DM, H1, DM, b1c, nullptr, 1.f, DM, 1, 0,0,0, 0,0,0, 0,0,0);
    // 5. FFN2: F = H1 @ w2^T + b2
    vgemm<false, true, false><<<dim3(4, 256, 1), 256, 0, stream>>>(
        H1, DM, w2c, DM, Ff, DM, b2c, nullptr, 1.f, DM, 1, 0,0,0, 0,0,0, 0,0,0);

    // 6. LN2: out = LN(F + X) -> FP32
    ln2_kernel<<<4096, 256, 0, stream>>>(Ff, Xf, gc, bc, out);
}

// Round 8
// 495.350 us; speedup vs baseline: 3.8768x; 3.8768x over previous
//
#include <hip/hip_runtime.h>
#include <stdint.h>

// ---------------------------------------------------------------------------
// TransformerBlock: B=32, L=512, D=256, H=4.
// Inputs fp32 (dict order, r7-confirmed); OUTPUT FP32 (r7-confirmed).
// MFMA bf16 GEMMs (fp32 accumulate); X and F fp32; P bf16 in-place over S.
// Adaptive workspace: fixed 27 MiB + chunk scratch max(9*CB,24) MiB.
// ---------------------------------------------------------------------------
#define SEQ   512
#define DM    256
#define NB    32
#define NH    4
#define HD    (NH * DM)           // 1024
#define PE_MASK (SEQ * DM - 1)    // 131071
#define NEGV  (-4294967295.0f)

typedef __attribute__((ext_vector_type(8))) short short8;   // 8 x bf16
typedef __attribute__((ext_vector_type(4))) float f32x4;    // MFMA accumulator

__device__ __forceinline__ float b2f(unsigned short u) {
    return __uint_as_float(((uint32_t)u) << 16);
}
__device__ __forceinline__ unsigned short f2b(float f) {
    uint32_t u = __float_as_uint(f);
    u += 0x7fffu + ((u >> 16) & 1u);   // RNE
    return (unsigned short)(u >> 16);
}

union U8 { unsigned short s[8]; uint4 v; };

// ---------------------------------------------------------------------------
// Canonicalize mask to int32 (auto-detect uint8 / int32 / int64) — r7-green.
// ---------------------------------------------------------------------------
__global__ __launch_bounds__(256) void mask_canon(
    const unsigned char* __restrict__ raw, int* __restrict__ canon)
{
    __shared__ int enc_byte, enc_odd;
    int tid = threadIdx.x;
    if (tid == 0) { enc_byte = 0; enc_odd = 0; }
    __syncthreads();
    if (tid < 255 && raw[tid * 4 + 1]) atomicOr(&enc_byte, 1);
    if (tid < 128 && ((const int*)raw)[tid * 2 + 1]) atomicOr(&enc_odd, 1);
    __syncthreads();
    int i = blockIdx.x * 256 + tid;
    int v;
    if (enc_byte)      v = (raw[i] != 0);
    else if (enc_odd)  v = (((const int*)raw)[i] != 0);
    else               v = ((((const int*)raw)[i * 2] | ((const int*)raw)[i * 2 + 1]) != 0);
    canon[i] = v;
}

// ---------------------------------------------------------------------------
// Transpose fp32 in -> bf16 out: out[c][r] = bf16(in[r][c]); 32x32 tiles.
// ---------------------------------------------------------------------------
__global__ __launch_bounds__(256) void transpose_f2b(
    const float* __restrict__ in, unsigned short* __restrict__ out,
    int ldin, int ldout)
{
    __shared__ unsigned short tile[32][33];
    int r0 = blockIdx.y * 32, c0 = blockIdx.x * 32;
    int i = threadIdx.x >> 3;
    int j = (threadIdx.x & 7) * 4;
    float4 v = *reinterpret_cast<const float4*>(in + (long)(r0 + i) * ldin + c0 + j);
    tile[i][j + 0] = f2b(v.x); tile[i][j + 1] = f2b(v.y);
    tile[i][j + 2] = f2b(v.z); tile[i][j + 3] = f2b(v.w);
    __syncthreads();
    ushort4 w;
    w.x = tile[j + 0][i]; w.y = tile[j + 1][i]; w.z = tile[j + 2][i]; w.w = tile[j + 3][i];
    *reinterpret_cast<ushort4*>(out + (long)(c0 + i) * ldout + r0 + j) = w;
}

// ---------------------------------------------------------------------------
// Batched bf16 transpose (per-head V): out[c][r] = in[r][c]
// ---------------------------------------------------------------------------
__global__ __launch_bounds__(256) void transpose_bf16(
    const unsigned short* __restrict__ in, unsigned short* __restrict__ out,
    int ldin, int ldout, long sInB, long sInH, long sOutB, long sOutH, int Hdiv)
{
    int z = blockIdx.z; int b = z / Hdiv; int h = z % Hdiv;
    const unsigned short* ip = in + b * sInB + h * sInH;
    unsigned short* op = out + b * sOutB + h * sOutH;
    __shared__ unsigned short tile[32][33];
    int r0 = blockIdx.y * 32, c0 = blockIdx.x * 32;
    int i = threadIdx.x >> 3;
    int j = (threadIdx.x & 7) * 4;
    ushort4 v = *reinterpret_cast<const ushort4*>(ip + (long)(r0 + i) * ldin + c0 + j);
    tile[i][j + 0] = v.x; tile[i][j + 1] = v.y; tile[i][j + 2] = v.z; tile[i][j + 3] = v.w;
    __syncthreads();
    ushort4 w;
    w.x = tile[j + 0][i]; w.y = tile[j + 1][i]; w.z = tile[j + 2][i]; w.w = tile[j + 3][i];
    *reinterpret_cast<ushort4*>(op + (long)(c0 + i) * ldout + r0 + j) = w;
}

// ---------------------------------------------------------------------------
// MFMA GEMM:  C[m][n] = scale * sum_k A[m][k] * Bt[n][k]  (+bias, relu)
// AMODE: 0 = A bf16; 1 = A fp32 + fused pe-add (pe row = m & 511); 2 = A fp32
// BMODE: 0 = Bt bf16; 1 = Bt fp32
// 128x128 tile/block, 4 waves, mfma_f32_16x16x32_bf16 (m97-verified layouts).
// ---------------------------------------------------------------------------
template<int AMODE, int BMODE, bool BIAS, bool RELU, bool OUTBF16>
__global__ __launch_bounds__(256) void gemm_bt(
    const void* __restrict__ Av, int lda,
    const void* __restrict__ Bv, int ldb,
    void* __restrict__ Cv, int ldc,
    const float* __restrict__ bias, const float* __restrict__ pe,
    float scale, int K, int Hdiv, int bh0,
    long sAb, long sAh, long sAz,
    long sBb, long sBh, long sBz,
    long sCb, long sCh, long sCz)
{
    int z  = blockIdx.z;
    int bh = bh0 + z;
    int bb = bh / Hdiv, hh = bh % Hdiv;
    long aoff = bb * sAb + hh * sAh + (long)z * sAz;
    long boff = bb * sBb + hh * sBh + (long)z * sBz;
    long coff = bb * sCb + hh * sCh + (long)z * sCz;

    const int m0 = blockIdx.y * 128;
    const int n0 = blockIdx.x * 128;

    __shared__ unsigned short As[128 * 32];
    __shared__ unsigned short Bs[128 * 32];

    const int tid  = threadIdx.x;
    const int lane = tid & 63;
    const int wave = tid >> 6;
    const int wm   = (wave >> 1) * 64;
    const int wn   = (wave & 1) * 64;
    const int lm   = lane & 15;
    const int kq   = (lane >> 4) * 8;

    f32x4 acc[4][4] = {};

    for (int k0 = 0; k0 < K; k0 += 32) {
#pragma unroll
        for (int it = 0; it < 2; ++it) {
            int id = tid + it * 256;
            int r  = id >> 2;
            int c8 = (id & 3) * 8;
            if (AMODE == 0) {
                *reinterpret_cast<uint4*>(&As[r * 32 + c8]) =
                    *reinterpret_cast<const uint4*>(
                        (const unsigned short*)Av + aoff + (long)(m0 + r) * lda + k0 + c8);
            } else {
                const float* Af = (const float*)Av;
                long base = aoff + (long)(m0 + r) * lda + k0 + c8;
                float4 x0 = *reinterpret_cast<const float4*>(Af + base);
                float4 x1 = *reinterpret_cast<const float4*>(Af + base + 4);
                U8 u;
                if (AMODE == 1) {
                    long pb = (long)((m0 + r) & (SEQ - 1)) * DM + k0 + c8;
                    float4 p0 = *reinterpret_cast<const float4*>(pe + pb);
                    float4 p1 = *reinterpret_cast<const float4*>(pe + pb + 4);
                    u.s[0] = f2b(x0.x + p0.x); u.s[1] = f2b(x0.y + p0.y);
                    u.s[2] = f2b(x0.z + p0.z); u.s[3] = f2b(x0.w + p0.w);
                    u.s[4] = f2b(x1.x + p1.x); u.s[5] = f2b(x1.y + p1.y);
                    u.s[6] = f2b(x1.z + p1.z); u.s[7] = f2b(x1.w + p1.w);
                } else {
                    u.s[0] = f2b(x0.x); u.s[1] = f2b(x0.y);
                    u.s[2] = f2b(x0.z); u.s[3] = f2b(x0.w);
                    u.s[4] = f2b(x1.x); u.s[5] = f2b(x1.y);
                    u.s[6] = f2b(x1.z); u.s[7] = f2b(x1.w);
                }
                *reinterpret_cast<uint4*>(&As[r * 32 + c8]) = u.v;
            }
            if (BMODE == 0) {
                *reinterpret_cast<uint4*>(&Bs[r * 32 + c8]) =
                    *reinterpret_cast<const uint4*>(
                        (const unsigned short*)Bv + boff + (long)(n0 + r) * ldb + k0 + c8);
            } else {
                const float* Bf = (const float*)Bv;
                long base = boff + (long)(n0 + r) * ldb + k0 + c8;
                float4 x0 = *reinterpret_cast<const float4*>(Bf + base);
                float4 x1 = *reinterpret_cast<const float4*>(Bf + base + 4);
                U8 u;
                u.s[0] = f2b(x0.x); u.s[1] = f2b(x0.y);
                u.s[2] = f2b(x0.z); u.s[3] = f2b(x0.w);
                u.s[4] = f2b(x1.x); u.s[5] = f2b(x1.y);
                u.s[6] = f2b(x1.z); u.s[7] = f2b(x1.w);
                *reinterpret_cast<uint4*>(&Bs[r * 32 + c8]) = u.v;
            }
        }
        __syncthreads();

        short8 af[4], bfr[4];
#pragma unroll
        for (int i = 0; i < 4; ++i)
            af[i] = *reinterpret_cast<const short8*>(&As[(wm + i * 16 + lm) * 32 + kq]);
#pragma unroll
        for (int j = 0; j < 4; ++j)
            bfr[j] = *reinterpret_cast<const short8*>(&Bs[(wn + j * 16 + lm) * 32 + kq]);
#pragma unroll
        for (int i = 0; i < 4; ++i)
#pragma unroll
            for (int j = 0; j < 4; ++j)
                acc[i][j] = __builtin_amdgcn_mfma_f32_16x16x32_bf16(af[i], bfr[j], acc[i][j], 0, 0, 0);
        __syncthreads();
    }

    // epilogue: C/D layout col = lane&15, row = (lane>>4)*4 + r  [m89-verified]
#pragma unroll
    for (int j = 0; j < 4; ++j) {
        int col  = n0 + wn + j * 16 + lm;
        float bv = 0.f;
        if (BIAS) bv = bias[col];
#pragma unroll
        for (int i = 0; i < 4; ++i) {
#pragma unroll
            for (int r = 0; r < 4; ++r) {
                int row = m0 + wm + i * 16 + (lane >> 4) * 4 + r;
                float v = acc[i][j][r] * scale + bv;
                if (RELU) v = fmaxf(v, 0.f);
                long idx = coff + (long)row * ldc + col;
                if (OUTBF16) reinterpret_cast<unsigned short*>(Cv)[idx] = f2b(v);
                else         reinterpret_cast<float*>(Cv)[idx] = v;
            }
        }
    }
}

// ---------------------------------------------------------------------------
// Masked softmax over 512-wide fp32 rows of chunk-local S; bf16 P in place.
// full_mask[q][k] = (k > q) || mask[b][q]; b from GLOBAL bh0+z.
// ---------------------------------------------------------------------------
__global__ __launch_bounds__(256) void softmax_kernel(
    float* __restrict__ S, const int* __restrict__ mask, int bh0)
{
    int row  = blockIdx.x * 4 + (threadIdx.x >> 6);
    int lane = threadIdx.x & 63;
    int z = row >> 9;
    int q = row & (SEQ - 1);
    int b = (bh0 + z) >> 2;
    bool rowmask = mask[b * SEQ + q] != 0;
    float* Srow = S + (long)row * SEQ;

    float4 v0 = reinterpret_cast<float4*>(Srow)[lane];
    float4 v1 = reinterpret_cast<float4*>(Srow)[64 + lane];
    float vals[8] = {v0.x, v0.y, v0.z, v0.w, v1.x, v1.y, v1.z, v1.w};
    int k0 = lane * 4;
#pragma unroll
    for (int t = 0; t < 8; ++t) {
        int k = (t < 4) ? (k0 + t) : (256 + k0 + (t - 4));
        if (k > q || rowmask) vals[t] = NEGV;
    }
    float mx = vals[0];
#pragma unroll
    for (int t = 1; t < 8; ++t) mx = fmaxf(mx, vals[t]);
#pragma unroll
    for (int off = 32; off > 0; off >>= 1) mx = fmaxf(mx, __shfl_xor(mx, off));
    float sum = 0.f;
#pragma unroll
    for (int t = 0; t < 8; ++t) { vals[t] = __expf(vals[t] - mx); sum += vals[t]; }
#pragma unroll
    for (int off = 32; off > 0; off >>= 1) sum += __shfl_xor(sum, off);
    float inv = 1.0f / sum;

    ushort4 o0, o1;
    o0.x = f2b(vals[0] * inv); o0.y = f2b(vals[1] * inv);
    o0.z = f2b(vals[2] * inv); o0.w = f2b(vals[3] * inv);
    o1.x = f2b(vals[4] * inv); o1.y = f2b(vals[5] * inv);
    o1.z = f2b(vals[6] * inv); o1.w = f2b(vals[7] * inv);
    ushort4* Prow = reinterpret_cast<ushort4*>(Srow);
    Prow[lane]      = o0;
    Prow[64 + lane] = o1;
}

// ---------------------------------------------------------------------------
// LN1: x = bf16 AttO + fp32 Q + fp32 pe  ->  fp32 X
// ---------------------------------------------------------------------------
__global__ __launch_bounds__(256) void ln1_kernel(
    const unsigned short* __restrict__ AttO, const float* __restrict__ Q,
    const float* __restrict__ pe,
    const float* __restrict__ gamma, const float* __restrict__ beta,
    float* __restrict__ out)
{
    int row  = blockIdx.x * 4 + (threadIdx.x >> 6);
    int lane = threadIdx.x & 63;
    long base = (long)row * DM + lane * 4;
    ushort4 a = *reinterpret_cast<const ushort4*>(AttO + base);
    float4 qv = *reinterpret_cast<const float4*>(Q + base);
    float4 pv = *reinterpret_cast<const float4*>(pe + (base & PE_MASK));
    float x[4] = {b2f(a.x) + qv.x + pv.x, b2f(a.y) + qv.y + pv.y,
                  b2f(a.z) + qv.z + pv.z, b2f(a.w) + qv.w + pv.w};
    float s = x[0] + x[1] + x[2] + x[3];
#pragma unroll
    for (int off = 32; off > 0; off >>= 1) s += __shfl_xor(s, off);
    float mu = s * (1.0f / DM);
    float vs = 0.f;
#pragma unroll
    for (int t = 0; t < 4; ++t) { float d = x[t] - mu; vs += d * d; }
#pragma unroll
    for (int off = 32; off > 0; off >>= 1) vs += __shfl_xor(vs, off);
    float inv = rsqrtf(vs * (1.0f / DM) + 1e-5f);
    int d0 = lane * 4;
    float4 g = *reinterpret_cast<const float4*>(gamma + d0);
    float4 bt = *reinterpret_cast<const float4*>(beta + d0);
    float4 o;
    o.x = (x[0] - mu) * inv * g.x + bt.x;
    o.y = (x[1] - mu) * inv * g.y + bt.y;
    o.z = (x[2] - mu) * inv * g.z + bt.z;
    o.w = (x[3] - mu) * inv * g.w + bt.w;
    *reinterpret_cast<float4*>(out + base) = o;
}

// ---------------------------------------------------------------------------
// LN2: x = fp32 F + fp32 X  ->  FP32 out (reference output dtype, r7-green)
// ---------------------------------------------------------------------------
__global__ __launch_bounds__(256) void ln2_kernel(
    const float* __restrict__ F, const float* __restrict__ X,
    const float* __restrict__ gamma, const float* __restrict__ beta,
    float* __restrict__ out)
{
    int row  = blockIdx.x * 4 + (threadIdx.x >> 6);
    int lane = threadIdx.x & 63;
    long base = (long)row * DM + lane * 4;
    float4 a = *reinterpret_cast<const float4*>(F + base);
    float4 c = *reinterpret_cast<const float4*>(X + base);
    float x[4] = {a.x + c.x, a.y + c.y, a.z + c.z, a.w + c.w};
    float s = x[0] + x[1] + x[2] + x[3];
#pragma unroll
    for (int off = 32; off > 0; off >>= 1) s += __shfl_xor(s, off);
    float mu = s * (1.0f / DM);
    float vs = 0.f;
#pragma unroll
    for (int t = 0; t < 4; ++t) { float d = x[t] - mu; vs += d * d; }
#pragma unroll
    for (int off = 32; off > 0; off >>= 1) vs += __shfl_xor(vs, off);
    float inv = rsqrtf(vs * (1.0f / DM) + 1e-5f);
    int d0 = lane * 4;
    float4 g = *reinterpret_cast<const float4*>(gamma + d0);
    float4 bt = *reinterpret_cast<const float4*>(beta + d0);
    float4 o;
    o.x = (x[0] - mu) * inv * g.x + bt.x;
    o.y = (x[1] - mu) * inv * g.y + bt.y;
    o.z = (x[2] - mu) * inv * g.z + bt.z;
    o.w = (x[3] - mu) * inv * g.w + bt.w;
    *reinterpret_cast<float4*>(out + base) = o;
}

// ---------------------------------------------------------------------------
extern "C" void kernel_launch(void* const* d_in, const int* in_sizes, int n_in,
                              void* d_out, int out_size, void* d_ws, size_t ws_size,
                              hipStream_t stream)
{
    const float* Q  = (const float*)d_in[0];
    const float* Ki = (const float*)d_in[1];
    const float* Vi = (const float*)d_in[2];
    const unsigned char* mask_raw = (const unsigned char*)d_in[3];
    const float* pe = (const float*)d_in[4];
    const float* Wq = (const float*)d_in[5];
    const float* Wk = (const float*)d_in[6];
    const float* Wv = (const float*)d_in[7];
    const float* Wo = (const float*)d_in[8];
    const float* w1 = (const float*)d_in[9];
    const float* b1 = (const float*)d_in[10];
    const float* w2 = (const float*)d_in[11];
    const float* b2 = (const float*)d_in[12];
    const float* gamma = (const float*)d_in[13];
    const float* beta  = (const float*)d_in[14];
    float* out = (float*)d_out;

    const size_t MiB = 1048576;
    char* ws = (char*)d_ws;

    // ---- adaptive chunk size: footprint = 27 + max(9*CB, 24) MiB ----
    int CB = 1;
    for (int cb = 32; cb >= 1; cb >>= 1) {
        size_t scr_sz = (size_t)(9 * cb) * MiB;
        if (scr_sz < 24 * MiB) scr_sz = 24 * MiB;
        if ((27 * MiB + scr_sz) <= ws_size) { CB = cb; break; }
    }
    const int NCH = NB / CB;

    // ---- fixed low regions ----
    unsigned short* WqT  = (unsigned short*)(ws);                 // 512 KiB each
    unsigned short* WkT  = WqT + 262144;
    unsigned short* WvT  = WkT + 262144;
    unsigned short* WoT  = WvT + 262144;
    int*            maskc = (int*)(ws + 2 * MiB);                 // 64 KiB
    unsigned short* AttO = (unsigned short*)(ws + 3 * MiB);       // 8 MiB bf16
    float*          Xf   = (float*)(ws + 11 * MiB);               // 16 MiB fp32
    char*           scr  = ws + 27 * MiB;
    // chunk scratch (CB MiB each, S = 4*CB MiB)
    unsigned short* Qh   = (unsigned short*)(scr);
    unsigned short* Kh   = (unsigned short*)(scr + (size_t)CB * MiB);
    unsigned short* Vh   = (unsigned short*)(scr + (size_t)2 * CB * MiB);
    unsigned short* VhT  = (unsigned short*)(scr + (size_t)3 * CB * MiB);
    unsigned short* Vatt = (unsigned short*)(scr + (size_t)4 * CB * MiB);
    float*          S    = (float*)(scr + (size_t)5 * CB * MiB);
    // tail aliases over scratch (chunk buffers dead by then)
    unsigned short* H1   = (unsigned short*)(scr);                // 8 MiB bf16
    float*          Ff   = (float*)(scr + 8 * MiB);               // 16 MiB fp32

    const float scale = (float)(1.0 / (16.0 + 1e-6));
    const long CROWS = (long)CB * SEQ;

    // 0. mask canonicalization + weight transposes (fp32 -> bf16 N x K)
    mask_canon<<<64, 256, 0, stream>>>(mask_raw, maskc);
    transpose_f2b<<<dim3(32, 8, 1), 256, 0, stream>>>(Wq, WqT, HD, DM);
    transpose_f2b<<<dim3(32, 8, 1), 256, 0, stream>>>(Wk, WkT, HD, DM);
    transpose_f2b<<<dim3(32, 8, 1), 256, 0, stream>>>(Wv, WvT, HD, DM);
    transpose_f2b<<<dim3(8, 32, 1), 256, 0, stream>>>(Wo, WoT, DM, HD);

    // 1. attention in NCH chunks of CB batches
    for (int c = 0; c < NCH; ++c) {
        const long r0   = (long)c * CROWS;
        const int  bh0  = c * CB * NH;
        const int  gy   = (int)(CROWS / 128);

        // projections (fused pe-add): fp32 rows [r0, r0+CROWS) -> bf16 Qh/Kh/Vh
        gemm_bt<1, 0, false, false, true><<<dim3(8, gy, 1), 256, 0, stream>>>(
            Q + r0 * DM, DM, WqT, DM, Qh, HD, nullptr, pe, 1.f, DM,
            1, 0, 0,0,0, 0,0,0, 0,0,0);
        gemm_bt<1, 0, false, false, true><<<dim3(8, gy, 1), 256, 0, stream>>>(
            Ki + r0 * DM, DM, WkT, DM, Kh, HD, nullptr, pe, 1.f, DM,
            1, 0, 0,0,0, 0,0,0, 0,0,0);
        gemm_bt<1, 0, false, false, true><<<dim3(8, gy, 1), 256, 0, stream>>>(
            Vi + r0 * DM, DM, WvT, DM, Vh, HD, nullptr, pe, 1.f, DM,
            1, 0, 0,0,0, 0,0,0, 0,0,0);

        // per-head V transpose: VhT[bl][h][d][l] = Vh[bl][l][h*256+d]
        transpose_bf16<<<dim3(8, 16, CB * NH), 256, 0, stream>>>(
            Vh, VhT, HD, SEQ, (long)SEQ * HD, DM, (long)SEQ * HD, (long)SEQ * DM, NH);

        // scores: S[z][q][k] = scale * Qh(z).Kh(z)^T   (fp32 out)
        gemm_bt<0, 0, false, false, false><<<dim3(4, 4, CB * NH), 256, 0, stream>>>(
            Qh, HD, Kh, HD, S, SEQ, nullptr, nullptr, scale, DM,
            NH, 0, (long)SEQ * HD, DM, 0, (long)SEQ * HD, DM, 0, 0, 0, (long)SEQ * SEQ);

        // masked softmax (global mask via bh0), bf16 P in place
        softmax_kernel<<<512 * CB, 256, 0, stream>>>(S, maskc, bh0);

        // PV: Vatt[bl][q][h*256+d] = P(z) . VhT(z)
        gemm_bt<0, 0, false, false, true><<<dim3(2, 4, CB * NH), 256, 0, stream>>>(
            S, HD, VhT, SEQ, Vatt, HD, nullptr, nullptr, 1.f, SEQ,
            NH, 0, 0, 0, (long)SEQ * HD, (long)SEQ * HD, (long)SEQ * DM, 0,
            (long)SEQ * HD, DM, 0);

        // output projection for this chunk -> AttO rows [r0, r0+CROWS)
        gemm_bt<0, 0, false, false, true><<<dim3(2, gy, 1), 256, 0, stream>>>(
            Vatt, HD, WoT, HD, AttO + r0 * DM, DM, nullptr, nullptr, 1.f, HD,
            1, 0, 0,0,0, 0,0,0, 0,0,0);
    }

    // 2. LN1: X = LN(Q + pe + AttO) -> fp32
    ln1_kernel<<<4096, 256, 0, stream>>>(AttO, Q, pe, gamma, beta, Xf);

    // 3. FFN1: H1 = relu(X @ w1^T + b1) -> bf16
    gemm_bt<2, 1, true, true, true><<<dim3(2, 128, 1), 256, 0, stream>>>(
        Xf, DM, w1, DM, H1, DM, b1, nullptr, 1.f, DM, 1, 0, 0,0,0, 0,0,0, 0,0,0);
    // 4. FFN2: F = H1 @ w2^T + b2 -> fp32
    gemm_bt<0, 1, true, false, false><<<dim3(2, 128, 1), 256, 0, stream>>>(
        H1, DM, w2, DM, Ff, DM, b2, nullptr, 1.f, DM, 1, 0, 0,0,0, 0,0,0, 0,0,0);

    // 5. LN2: out = LN(F + X) -> FP32
    ln2_kernel<<<4096, 256, 0, stream>>>(Ff, Xf, gamma, beta, out);
}

// Round 9
// 468.210 us; speedup vs baseline: 4.1016x; 1.0580x over previous
//
#include <hip/hip_runtime.h>
#include <stdint.h>

// ---------------------------------------------------------------------------
// TransformerBlock: B=32, L=512, D=256, H=4.
// Inputs fp32 (dict order); OUTPUT fp32. All GEMMs pure bf16 MFMA with
// global_load_lds width-16 staging (m97 pattern); fp32 accumulate.
// S fp32; P bf16 in place; X/F fp32 residuals. Causal tile-skip in scores.
// ws ~ 59 + 9*CB MiB (adaptive CB; ws ≈ 268 MB -> CB = 16, 2 chunks).
// ---------------------------------------------------------------------------
#define SEQ   512
#define DM    256
#define NB    32
#define NH    4
#define HD    (NH * DM)           // 1024
#define PE_MASK (SEQ * DM - 1)    // 131071
#define NEGV  (-4294967295.0f)

typedef __attribute__((ext_vector_type(8))) short short8;   // 8 x bf16
typedef __attribute__((ext_vector_type(4))) float f32x4;    // MFMA accumulator

#if defined(__has_builtin)
#if __has_builtin(__builtin_amdgcn_global_load_lds)
#define HAS_ASYNC 1
#endif
#endif
#ifndef HAS_ASYNC
#define HAS_ASYNC 0
#endif

__device__ __forceinline__ float b2f(unsigned short u) {
    return __uint_as_float(((uint32_t)u) << 16);
}
__device__ __forceinline__ unsigned short f2b(float f) {
    uint32_t u = __float_as_uint(f);
    u += 0x7fffu + ((u >> 16) & 1u);   // RNE
    return (unsigned short)(u >> 16);
}

// ---------------------------------------------------------------------------
// Canonicalize mask to int32 (auto-detect uint8 / int32 / int64) — r7-green.
// ---------------------------------------------------------------------------
__global__ __launch_bounds__(256) void mask_canon(
    const unsigned char* __restrict__ raw, int* __restrict__ canon)
{
    __shared__ int enc_byte, enc_odd;
    int tid = threadIdx.x;
    if (tid == 0) { enc_byte = 0; enc_odd = 0; }
    __syncthreads();
    if (tid < 255 && raw[tid * 4 + 1]) atomicOr(&enc_byte, 1);
    if (tid < 128 && ((const int*)raw)[tid * 2 + 1]) atomicOr(&enc_odd, 1);
    __syncthreads();
    int i = blockIdx.x * 256 + tid;
    int v;
    if (enc_byte)      v = (raw[i] != 0);
    else if (enc_odd)  v = (((const int*)raw)[i] != 0);
    else               v = ((((const int*)raw)[i * 2] | ((const int*)raw)[i * 2 + 1]) != 0);
    canon[i] = v;
}

// ---------------------------------------------------------------------------
// addpe_f2b: out_bf16[i] = bf16(X[i] + pe[i mod 512*256]); 4 elems/thread.
// ---------------------------------------------------------------------------
__global__ __launch_bounds__(256) void addpe_f2b(
    const float* __restrict__ X, const float* __restrict__ pe,
    unsigned short* __restrict__ out)
{
    long i = (long)(blockIdx.x * 256 + threadIdx.x) * 4;
    float4 x = *reinterpret_cast<const float4*>(X + i);
    float4 p = *reinterpret_cast<const float4*>(pe + (i & PE_MASK));
    ushort4 o;
    o.x = f2b(x.x + p.x); o.y = f2b(x.y + p.y);
    o.z = f2b(x.z + p.z); o.w = f2b(x.w + p.w);
    *reinterpret_cast<ushort4*>(out + i) = o;
}

// ---------------------------------------------------------------------------
// conv_f2b: plain fp32 -> bf16, 4 elems/thread (weights).
// ---------------------------------------------------------------------------
__global__ __launch_bounds__(256) void conv_f2b(
    const float* __restrict__ in, unsigned short* __restrict__ out)
{
    long i = (long)(blockIdx.x * 256 + threadIdx.x) * 4;
    float4 x = *reinterpret_cast<const float4*>(in + i);
    ushort4 o;
    o.x = f2b(x.x); o.y = f2b(x.y); o.z = f2b(x.z); o.w = f2b(x.w);
    *reinterpret_cast<ushort4*>(out + i) = o;
}

// ---------------------------------------------------------------------------
// Transpose fp32 in -> bf16 out: out[c][r] = bf16(in[r][c]); 32x32 tiles.
// ---------------------------------------------------------------------------
__global__ __launch_bounds__(256) void transpose_f2b(
    const float* __restrict__ in, unsigned short* __restrict__ out,
    int ldin, int ldout)
{
    __shared__ unsigned short tile[32][33];
    int r0 = blockIdx.y * 32, c0 = blockIdx.x * 32;
    int i = threadIdx.x >> 3;
    int j = (threadIdx.x & 7) * 4;
    float4 v = *reinterpret_cast<const float4*>(in + (long)(r0 + i) * ldin + c0 + j);
    tile[i][j + 0] = f2b(v.x); tile[i][j + 1] = f2b(v.y);
    tile[i][j + 2] = f2b(v.z); tile[i][j + 3] = f2b(v.w);
    __syncthreads();
    ushort4 w;
    w.x = tile[j + 0][i]; w.y = tile[j + 1][i]; w.z = tile[j + 2][i]; w.w = tile[j + 3][i];
    *reinterpret_cast<ushort4*>(out + (long)(c0 + i) * ldout + r0 + j) = w;
}

// ---------------------------------------------------------------------------
// Batched bf16 transpose (per-head V): out[c][r] = in[r][c]
// ---------------------------------------------------------------------------
__global__ __launch_bounds__(256) void transpose_bf16(
    const unsigned short* __restrict__ in, unsigned short* __restrict__ out,
    int ldin, int ldout, long sInB, long sInH, long sOutB, long sOutH, int Hdiv)
{
    int z = blockIdx.z; int b = z / Hdiv; int h = z % Hdiv;
    const unsigned short* ip = in + b * sInB + h * sInH;
    unsigned short* op = out + b * sOutB + h * sOutH;
    __shared__ unsigned short tile[32][33];
    int r0 = blockIdx.y * 32, c0 = blockIdx.x * 32;
    int i = threadIdx.x >> 3;
    int j = (threadIdx.x & 7) * 4;
    ushort4 v = *reinterpret_cast<const ushort4*>(ip + (long)(r0 + i) * ldin + c0 + j);
    tile[i][j + 0] = v.x; tile[i][j + 1] = v.y; tile[i][j + 2] = v.z; tile[i][j + 3] = v.w;
    __syncthreads();
    ushort4 w;
    w.x = tile[j + 0][i]; w.y = tile[j + 1][i]; w.z = tile[j + 2][i]; w.w = tile[j + 3][i];
    *reinterpret_cast<ushort4*>(op + (long)(c0 + i) * ldout + r0 + j) = w;
}

// ---------------------------------------------------------------------------
// Pure-bf16 MFMA GEMM: C[m][n] = scale * sum_k A[m][k] * Bt[n][k] (+bias,relu)
// 128x128 tile/block, 4 waves, mfma_f32_16x16x32_bf16 (m97-verified layouts).
// global_load_lds width-16 staging (LDS dest = wave base + lane*16).
// CAUSAL==1: skip blocks fully above the diagonal (scores only — safe because
// softmax replaces all masked entries; do NOT K-limit PV: pad-masked rows
// attend uniformly to all 512 keys).
// Batched via blockIdx.z: bb=z/Hdiv, hh=z%Hdiv.
// ---------------------------------------------------------------------------
template<int CAUSAL, bool BIAS, bool RELU, bool OUTBF16>
__global__ __launch_bounds__(256) void gemm_bt(
    const unsigned short* __restrict__ A, int lda,
    const unsigned short* __restrict__ B, int ldb,
    void* __restrict__ Cv, int ldc,
    const float* __restrict__ bias, float scale, int K, int Hdiv,
    long sAb, long sAh, long sAz,
    long sBb, long sBh, long sBz,
    long sCb, long sCh, long sCz)
{
    const int m0 = blockIdx.y * 128;
    const int n0 = blockIdx.x * 128;
    if (CAUSAL == 1 && n0 > m0 + 127) return;   // fully-masked score tile

    int z  = blockIdx.z;
    int bb = z / Hdiv, hh = z % Hdiv;
    const unsigned short* Ab = A + bb * sAb + hh * sAh + (long)z * sAz;
    const unsigned short* Bb = B + bb * sBb + hh * sBh + (long)z * sBz;
    long coff = bb * sCb + hh * sCh + (long)z * sCz;

    __shared__ unsigned short As[128 * 32];
    __shared__ unsigned short Bs[128 * 32];

    const int tid  = threadIdx.x;
    const int lane = tid & 63;
    const int wave = tid >> 6;
    const int wm   = (wave >> 1) * 64;
    const int wn   = (wave & 1) * 64;
    const int lm   = lane & 15;
    const int kq   = (lane >> 4) * 8;

    f32x4 acc[4][4] = {};

    for (int k0 = 0; k0 < K; k0 += 32) {
#pragma unroll
        for (int it = 0; it < 2; ++it) {
            int id = tid + it * 256;
            int r  = id >> 2;
            int c8 = (id & 3) * 8;
            const unsigned short* gA = Ab + (long)(m0 + r) * lda + k0 + c8;
            const unsigned short* gB = Bb + (long)(n0 + r) * ldb + k0 + c8;
#if HAS_ASYNC
            // LDS dest: wave-uniform base; HW scatters lane i to base + i*16B.
            unsigned short* lA = &As[(size_t)(it * 256 + wave * 64) * 8];
            unsigned short* lB = &Bs[(size_t)(it * 256 + wave * 64) * 8];
            __builtin_amdgcn_global_load_lds(
                (const __attribute__((address_space(1))) void*)gA,
                (__attribute__((address_space(3))) void*)lA, 16, 0, 0);
            __builtin_amdgcn_global_load_lds(
                (const __attribute__((address_space(1))) void*)gB,
                (__attribute__((address_space(3))) void*)lB, 16, 0, 0);
#else
            *reinterpret_cast<uint4*>(&As[(size_t)id * 8]) =
                *reinterpret_cast<const uint4*>(gA);
            *reinterpret_cast<uint4*>(&Bs[(size_t)id * 8]) =
                *reinterpret_cast<const uint4*>(gB);
#endif
        }
        __syncthreads();   // drains vmcnt (incl. global_load_lds) + lgkmcnt

        short8 af[4], bfr[4];
#pragma unroll
        for (int i = 0; i < 4; ++i)
            af[i] = *reinterpret_cast<const short8*>(&As[(wm + i * 16 + lm) * 32 + kq]);
#pragma unroll
        for (int j = 0; j < 4; ++j)
            bfr[j] = *reinterpret_cast<const short8*>(&Bs[(wn + j * 16 + lm) * 32 + kq]);
#pragma unroll
        for (int i = 0; i < 4; ++i)
#pragma unroll
            for (int j = 0; j < 4; ++j)
                acc[i][j] = __builtin_amdgcn_mfma_f32_16x16x32_bf16(af[i], bfr[j], acc[i][j], 0, 0, 0);
        __syncthreads();
    }

    // epilogue: C/D layout col = lane&15, row = (lane>>4)*4 + r  [m89-verified]
#pragma unroll
    for (int j = 0; j < 4; ++j) {
        int col  = n0 + wn + j * 16 + lm;
        float bv = 0.f;
        if (BIAS) bv = bias[col];
#pragma unroll
        for (int i = 0; i < 4; ++i) {
#pragma unroll
            for (int r = 0; r < 4; ++r) {
                int row = m0 + wm + i * 16 + (lane >> 4) * 4 + r;
                float v = acc[i][j][r] * scale + bv;
                if (RELU) v = fmaxf(v, 0.f);
                long idx = coff + (long)row * ldc + col;
                if (OUTBF16) reinterpret_cast<unsigned short*>(Cv)[idx] = f2b(v);
                else         reinterpret_cast<float*>(Cv)[idx] = v;
            }
        }
    }
}

// ---------------------------------------------------------------------------
// Masked softmax over 512-wide fp32 rows of chunk-local S; bf16 P in place.
// full_mask[q][k] = (k > q) || mask[b][q]; b from GLOBAL bh0+z.
// Pad-masked rows -> all NEGV -> uniform 1/512 over ALL k (matches reference).
// ---------------------------------------------------------------------------
__global__ __launch_bounds__(256) void softmax_kernel(
    float* __restrict__ S, const int* __restrict__ mask, int bh0)
{
    int row  = blockIdx.x * 4 + (threadIdx.x >> 6);
    int lane = threadIdx.x & 63;
    int z = row >> 9;
    int q = row & (SEQ - 1);
    int b = (bh0 + z) >> 2;
    bool rowmask = mask[b * SEQ + q] != 0;
    float* Srow = S + (long)row * SEQ;

    float4 v0 = reinterpret_cast<float4*>(Srow)[lane];
    float4 v1 = reinterpret_cast<float4*>(Srow)[64 + lane];
    float vals[8] = {v0.x, v0.y, v0.z, v0.w, v1.x, v1.y, v1.z, v1.w};
    int k0 = lane * 4;
#pragma unroll
    for (int t = 0; t < 8; ++t) {
        int k = (t < 4) ? (k0 + t) : (256 + k0 + (t - 4));
        if (k > q || rowmask) vals[t] = NEGV;
    }
    float mx = vals[0];
#pragma unroll
    for (int t = 1; t < 8; ++t) mx = fmaxf(mx, vals[t]);
#pragma unroll
    for (int off = 32; off > 0; off >>= 1) mx = fmaxf(mx, __shfl_xor(mx, off));
    float sum = 0.f;
#pragma unroll
    for (int t = 0; t < 8; ++t) { vals[t] = __expf(vals[t] - mx); sum += vals[t]; }
#pragma unroll
    for (int off = 32; off > 0; off >>= 1) sum += __shfl_xor(sum, off);
    float inv = 1.0f / sum;

    ushort4 o0, o1;
    o0.x = f2b(vals[0] * inv); o0.y = f2b(vals[1] * inv);
    o0.z = f2b(vals[2] * inv); o0.w = f2b(vals[3] * inv);
    o1.x = f2b(vals[4] * inv); o1.y = f2b(vals[5] * inv);
    o1.z = f2b(vals[6] * inv); o1.w = f2b(vals[7] * inv);
    ushort4* Prow = reinterpret_cast<ushort4*>(Srow);
    Prow[lane]      = o0;
    Prow[64 + lane] = o1;
}

// ---------------------------------------------------------------------------
// LN1: x = bf16 AttO + fp32 Q + fp32 pe  ->  fp32 Xf AND bf16 Xb
// ---------------------------------------------------------------------------
__global__ __launch_bounds__(256) void ln1_kernel(
    const unsigned short* __restrict__ AttO, const float* __restrict__ Q,
    const float* __restrict__ pe,
    const float* __restrict__ gamma, const float* __restrict__ beta,
    float* __restrict__ outf, unsigned short* __restrict__ outb)
{
    int row  = blockIdx.x * 4 + (threadIdx.x >> 6);
    int lane = threadIdx.x & 63;
    long base = (long)row * DM + lane * 4;
    ushort4 a = *reinterpret_cast<const ushort4*>(AttO + base);
    float4 qv = *reinterpret_cast<const float4*>(Q + base);
    float4 pv = *reinterpret_cast<const float4*>(pe + (base & PE_MASK));
    float x[4] = {b2f(a.x) + qv.x + pv.x, b2f(a.y) + qv.y + pv.y,
                  b2f(a.z) + qv.z + pv.z, b2f(a.w) + qv.w + pv.w};
    float s = x[0] + x[1] + x[2] + x[3];
#pragma unroll
    for (int off = 32; off > 0; off >>= 1) s += __shfl_xor(s, off);
    float mu = s * (1.0f / DM);
    float vs = 0.f;
#pragma unroll
    for (int t = 0; t < 4; ++t) { float d = x[t] - mu; vs += d * d; }
#pragma unroll
    for (int off = 32; off > 0; off >>= 1) vs += __shfl_xor(vs, off);
    float inv = rsqrtf(vs * (1.0f / DM) + 1e-5f);
    int d0 = lane * 4;
    float4 g = *reinterpret_cast<const float4*>(gamma + d0);
    float4 bt = *reinterpret_cast<const float4*>(beta + d0);
    float4 o;
    o.x = (x[0] - mu) * inv * g.x + bt.x;
    o.y = (x[1] - mu) * inv * g.y + bt.y;
    o.z = (x[2] - mu) * inv * g.z + bt.z;
    o.w = (x[3] - mu) * inv * g.w + bt.w;
    *reinterpret_cast<float4*>(outf + base) = o;
    ushort4 ob;
    ob.x = f2b(o.x); ob.y = f2b(o.y); ob.z = f2b(o.z); ob.w = f2b(o.w);
    *reinterpret_cast<ushort4*>(outb + base) = ob;
}

// ---------------------------------------------------------------------------
// LN2: x = fp32 F + fp32 X  ->  FP32 out
// ---------------------------------------------------------------------------
__global__ __launch_bounds__(256) void ln2_kernel(
    const float* __restrict__ F, const float* __restrict__ X,
    const float* __restrict__ gamma, const float* __restrict__ beta,
    float* __restrict__ out)
{
    int row  = blockIdx.x * 4 + (threadIdx.x >> 6);
    int lane = threadIdx.x & 63;
    long base = (long)row * DM + lane * 4;
    float4 a = *reinterpret_cast<const float4*>(F + base);
    float4 c = *reinterpret_cast<const float4*>(X + base);
    float x[4] = {a.x + c.x, a.y + c.y, a.z + c.z, a.w + c.w};
    float s = x[0] + x[1] + x[2] + x[3];
#pragma unroll
    for (int off = 32; off > 0; off >>= 1) s += __shfl_xor(s, off);
    float mu = s * (1.0f / DM);
    float vs = 0.f;
#pragma unroll
    for (int t = 0; t < 4; ++t) { float d = x[t] - mu; vs += d * d; }
#pragma unroll
    for (int off = 32; off > 0; off >>= 1) vs += __shfl_xor(vs, off);
    float inv = rsqrtf(vs * (1.0f / DM) + 1e-5f);
    int d0 = lane * 4;
    float4 g = *reinterpret_cast<const float4*>(gamma + d0);
    float4 bt = *reinterpret_cast<const float4*>(beta + d0);
    float4 o;
    o.x = (x[0] - mu) * inv * g.x + bt.x;
    o.y = (x[1] - mu) * inv * g.y + bt.y;
    o.z = (x[2] - mu) * inv * g.z + bt.z;
    o.w = (x[3] - mu) * inv * g.w + bt.w;
    *reinterpret_cast<float4*>(out + base) = o;
}

// ---------------------------------------------------------------------------
extern "C" void kernel_launch(void* const* d_in, const int* in_sizes, int n_in,
                              void* d_out, int out_size, void* d_ws, size_t ws_size,
                              hipStream_t stream)
{
    const float* Q  = (const float*)d_in[0];
    const float* Ki = (const float*)d_in[1];
    const float* Vi = (const float*)d_in[2];
    const unsigned char* mask_raw = (const unsigned char*)d_in[3];
    const float* pe = (const float*)d_in[4];
    const float* Wq = (const float*)d_in[5];
    const float* Wk = (const float*)d_in[6];
    const float* Wv = (const float*)d_in[7];
    const float* Wo = (const float*)d_in[8];
    const float* w1 = (const float*)d_in[9];
    const float* b1 = (const float*)d_in[10];
    const float* w2 = (const float*)d_in[11];
    const float* b2 = (const float*)d_in[12];
    const float* gamma = (const float*)d_in[13];
    const float* beta  = (const float*)d_in[14];
    float* out = (float*)d_out;

    const size_t MiB = 1048576;
    char* ws = (char*)d_ws;

    // ---- adaptive chunk size: footprint = 59 + max(9*CB, 24) MiB ----
    int CB = 1;
    for (int cb = 32; cb >= 1; cb >>= 1) {
        size_t scr_sz = (size_t)(9 * cb) * MiB;
        if (scr_sz < 24 * MiB) scr_sz = 24 * MiB;
        if ((59 * MiB + scr_sz) <= ws_size) { CB = cb; break; }
    }
    const int NCH = NB / CB;

    // ---- fixed low regions ----
    unsigned short* WqT  = (unsigned short*)(ws);                 // 512 KiB each
    unsigned short* WkT  = WqT + 262144;
    unsigned short* WvT  = WkT + 262144;
    unsigned short* WoT  = WvT + 262144;
    unsigned short* w1b  = (unsigned short*)(ws + 2 * MiB);       // 128 KiB
    unsigned short* w2b  = w1b + 65536;                           // 128 KiB
    int*            maskc = (int*)(ws + 2 * MiB + 262144);        // 64 KiB
    unsigned short* Qp   = (unsigned short*)(ws + 3 * MiB);       // 8 MiB bf16
    unsigned short* Kp   = (unsigned short*)(ws + 11 * MiB);      // 8 MiB
    unsigned short* Vp   = (unsigned short*)(ws + 19 * MiB);      // 8 MiB
    unsigned short* AttO = (unsigned short*)(ws + 27 * MiB);      // 8 MiB
    unsigned short* Xb   = (unsigned short*)(ws + 35 * MiB);      // 8 MiB
    float*          Xf   = (float*)(ws + 43 * MiB);               // 16 MiB
    char*           scr  = ws + 59 * MiB;
    // chunk scratch (CB MiB each, S = 4*CB MiB)
    unsigned short* Qh   = (unsigned short*)(scr);
    unsigned short* Kh   = (unsigned short*)(scr + (size_t)CB * MiB);
    unsigned short* Vh   = (unsigned short*)(scr + (size_t)2 * CB * MiB);
    unsigned short* VhT  = (unsigned short*)(scr + (size_t)3 * CB * MiB);
    unsigned short* Vatt = (unsigned short*)(scr + (size_t)4 * CB * MiB);
    float*          S    = (float*)(scr + (size_t)5 * CB * MiB);
    // tail aliases over scratch (chunk buffers dead by then)
    unsigned short* H1   = (unsigned short*)(scr);                // 8 MiB bf16
    float*          Ff   = (float*)(scr + 8 * MiB);               // 16 MiB fp32

    const float scale = (float)(1.0 / (16.0 + 1e-6));
    const long CROWS = (long)CB * SEQ;

    // 0. prep: mask, weight transposes/conversions, fused PE-add to bf16
    mask_canon<<<64, 256, 0, stream>>>(mask_raw, maskc);
    transpose_f2b<<<dim3(32, 8, 1), 256, 0, stream>>>(Wq, WqT, HD, DM);
    transpose_f2b<<<dim3(32, 8, 1), 256, 0, stream>>>(Wk, WkT, HD, DM);
    transpose_f2b<<<dim3(32, 8, 1), 256, 0, stream>>>(Wv, WvT, HD, DM);
    transpose_f2b<<<dim3(8, 32, 1), 256, 0, stream>>>(Wo, WoT, DM, HD);
    conv_f2b<<<64, 256, 0, stream>>>(w1, w1b);
    conv_f2b<<<64, 256, 0, stream>>>(w2, w2b);
    addpe_f2b<<<4096, 256, 0, stream>>>(Q,  pe, Qp);
    addpe_f2b<<<4096, 256, 0, stream>>>(Ki, pe, Kp);
    addpe_f2b<<<4096, 256, 0, stream>>>(Vi, pe, Vp);

    // 1. attention in NCH chunks of CB batches
    for (int c = 0; c < NCH; ++c) {
        const long r0   = (long)c * CROWS;
        const int  bh0  = c * CB * NH;
        const int  gy   = (int)(CROWS / 128);

        // projections: bf16 (X+pe) @ WxT -> bf16 Qh/Kh/Vh (chunk-local)
        gemm_bt<0, false, false, true><<<dim3(8, gy, 1), 256, 0, stream>>>(
            Qp + r0 * DM, DM, WqT, DM, Qh, HD, nullptr, 1.f, DM,
            1, 0,0,0, 0,0,0, 0,0,0);
        gemm_bt<0, false, false, true><<<dim3(8, gy, 1), 256, 0, stream>>>(
            Kp + r0 * DM, DM, WkT, DM, Kh, HD, nullptr, 1.f, DM,
            1, 0,0,0, 0,0,0, 0,0,0);
        gemm_bt<0, false, false, true><<<dim3(8, gy, 1), 256, 0, stream>>>(
            Vp + r0 * DM, DM, WvT, DM, Vh, HD, nullptr, 1.f, DM,
            1, 0,0,0, 0,0,0, 0,0,0);

        // per-head V transpose: VhT[bl][h][d][l] = Vh[bl][l][h*256+d]
        transpose_bf16<<<dim3(8, 16, CB * NH), 256, 0, stream>>>(
            Vh, VhT, HD, SEQ, (long)SEQ * HD, DM, (long)SEQ * HD, (long)SEQ * DM, NH);

        // scores: S[z][q][k] = scale * Qh(z).Kh(z)^T (fp32), causal tile-skip
        gemm_bt<1, false, false, false><<<dim3(4, 4, CB * NH), 256, 0, stream>>>(
            Qh, HD, Kh, HD, S, SEQ, nullptr, scale, DM,
            NH, (long)SEQ * HD, DM, 0, (long)SEQ * HD, DM, 0, 0, 0, (long)SEQ * SEQ);

        // masked softmax (global mask via bh0), bf16 P in place
        softmax_kernel<<<512 * CB, 256, 0, stream>>>(S, maskc, bh0);

        // PV (FULL K — pad-masked rows attend to all 512 keys)
        gemm_bt<0, false, false, true><<<dim3(2, 4, CB * NH), 256, 0, stream>>>(
            (const unsigned short*)S, HD, VhT, SEQ, Vatt, HD, nullptr, 1.f, SEQ,
            NH, 0, 0, (long)SEQ * HD, (long)SEQ * HD, (long)SEQ * DM, 0,
            (long)SEQ * HD, DM, 0);

        // output projection for this chunk -> AttO rows [r0, r0+CROWS)
        gemm_bt<0, false, false, true><<<dim3(2, gy, 1), 256, 0, stream>>>(
            Vatt, HD, WoT, HD, AttO + r0 * DM, DM, nullptr, 1.f, HD,
            1, 0,0,0, 0,0,0, 0,0,0);
    }

    // 2. LN1: X = LN(Q + pe + AttO) -> fp32 Xf + bf16 Xb
    ln1_kernel<<<4096, 256, 0, stream>>>(AttO, Q, pe, gamma, beta, Xf, Xb);

    // 3. FFN1: H1 = relu(Xb @ w1^T + b1) -> bf16
    gemm_bt<0, true, true, true><<<dim3(2, 128, 1), 256, 0, stream>>>(
        Xb, DM, w1b, DM, H1, DM, b1, 1.f, DM, 1, 0,0,0, 0,0,0, 0,0,0);
    // 4. FFN2: F = H1 @ w2^T + b2 -> fp32
    gemm_bt<0, true, false, false><<<dim3(2, 128, 1), 256, 0, stream>>>(
        H1, DM, w2b, DM, Ff, DM, b2, 1.f, DM, 1, 0,0,0, 0,0,0, 0,0,0);

    // 5. LN2: out = LN(F + X) -> FP32
    ln2_kernel<<<4096, 256, 0, stream>>>(Ff, Xf, gamma, beta, out);
}

// Round 10
// 423.361 us; speedup vs baseline: 4.5361x; 1.1059x over previous
//
#include <hip/hip_runtime.h>
#include <stdint.h>

// ---------------------------------------------------------------------------
// TransformerBlock: B=32, L=512, D=256, H=4.
// Inputs fp32 (dict order); OUTPUT fp32.
// bf16 MFMA GEMMs + FUSED flash-style attention (QK^T -> softmax -> PV in one
// kernel; S in registers, P via per-wave LDS, K/V via global_load_lds).
// ws = 59 + 5*CB MiB (CB=32 single chunk at ws=256MiB).
// ---------------------------------------------------------------------------
#define SEQ   512
#define DM    256
#define NB    32
#define NH    4
#define HD    (NH * DM)           // 1024
#define PE_MASK (SEQ * DM - 1)    // 131071
#define NEGV  (-4294967295.0f)

typedef __attribute__((ext_vector_type(8))) short short8;   // 8 x bf16
typedef __attribute__((ext_vector_type(4))) float f32x4;    // MFMA accumulator

#if defined(__has_builtin)
#if __has_builtin(__builtin_amdgcn_global_load_lds)
#define HAS_ASYNC 1
#endif
#endif
#ifndef HAS_ASYNC
#define HAS_ASYNC 0
#endif

__device__ __forceinline__ float b2f(unsigned short u) {
    return __uint_as_float(((uint32_t)u) << 16);
}
__device__ __forceinline__ unsigned short f2b(float f) {
    uint32_t u = __float_as_uint(f);
    u += 0x7fffu + ((u >> 16) & 1u);   // RNE
    return (unsigned short)(u >> 16);
}

// ---------------------------------------------------------------------------
// Canonicalize mask to int32 (auto-detect uint8 / int32 / int64) — r7-green.
// ---------------------------------------------------------------------------
__global__ __launch_bounds__(256) void mask_canon(
    const unsigned char* __restrict__ raw, int* __restrict__ canon)
{
    __shared__ int enc_byte, enc_odd;
    int tid = threadIdx.x;
    if (tid == 0) { enc_byte = 0; enc_odd = 0; }
    __syncthreads();
    if (tid < 255 && raw[tid * 4 + 1]) atomicOr(&enc_byte, 1);
    if (tid < 128 && ((const int*)raw)[tid * 2 + 1]) atomicOr(&enc_odd, 1);
    __syncthreads();
    int i = blockIdx.x * 256 + tid;
    int v;
    if (enc_byte)      v = (raw[i] != 0);
    else if (enc_odd)  v = (((const int*)raw)[i] != 0);
    else               v = ((((const int*)raw)[i * 2] | ((const int*)raw)[i * 2 + 1]) != 0);
    canon[i] = v;
}

// ---------------------------------------------------------------------------
// addpe_f2b: out_bf16[i] = bf16(X[i] + pe[i mod 512*256]); 4 elems/thread.
// ---------------------------------------------------------------------------
__global__ __launch_bounds__(256) void addpe_f2b(
    const float* __restrict__ X, const float* __restrict__ pe,
    unsigned short* __restrict__ out)
{
    long i = (long)(blockIdx.x * 256 + threadIdx.x) * 4;
    float4 x = *reinterpret_cast<const float4*>(X + i);
    float4 p = *reinterpret_cast<const float4*>(pe + (i & PE_MASK));
    ushort4 o;
    o.x = f2b(x.x + p.x); o.y = f2b(x.y + p.y);
    o.z = f2b(x.z + p.z); o.w = f2b(x.w + p.w);
    *reinterpret_cast<ushort4*>(out + i) = o;
}

__global__ __launch_bounds__(256) void conv_f2b(
    const float* __restrict__ in, unsigned short* __restrict__ out)
{
    long i = (long)(blockIdx.x * 256 + threadIdx.x) * 4;
    float4 x = *reinterpret_cast<const float4*>(in + i);
    ushort4 o;
    o.x = f2b(x.x); o.y = f2b(x.y); o.z = f2b(x.z); o.w = f2b(x.w);
    *reinterpret_cast<ushort4*>(out + i) = o;
}

// ---------------------------------------------------------------------------
// Transpose fp32 in -> bf16 out: out[c][r] = bf16(in[r][c]); 32x32 tiles.
// ---------------------------------------------------------------------------
__global__ __launch_bounds__(256) void transpose_f2b(
    const float* __restrict__ in, unsigned short* __restrict__ out,
    int ldin, int ldout)
{
    __shared__ unsigned short tile[32][33];
    int r0 = blockIdx.y * 32, c0 = blockIdx.x * 32;
    int i = threadIdx.x >> 3;
    int j = (threadIdx.x & 7) * 4;
    float4 v = *reinterpret_cast<const float4*>(in + (long)(r0 + i) * ldin + c0 + j);
    tile[i][j + 0] = f2b(v.x); tile[i][j + 1] = f2b(v.y);
    tile[i][j + 2] = f2b(v.z); tile[i][j + 3] = f2b(v.w);
    __syncthreads();
    ushort4 w;
    w.x = tile[j + 0][i]; w.y = tile[j + 1][i]; w.z = tile[j + 2][i]; w.w = tile[j + 3][i];
    *reinterpret_cast<ushort4*>(out + (long)(c0 + i) * ldout + r0 + j) = w;
}

// ---------------------------------------------------------------------------
// Batched bf16 transpose (per-head V): out[c][r] = in[r][c]
// ---------------------------------------------------------------------------
__global__ __launch_bounds__(256) void transpose_bf16(
    const unsigned short* __restrict__ in, unsigned short* __restrict__ out,
    int ldin, int ldout, long sInB, long sInH, long sOutB, long sOutH, int Hdiv)
{
    int z = blockIdx.z; int b = z / Hdiv; int h = z % Hdiv;
    const unsigned short* ip = in + b * sInB + h * sInH;
    unsigned short* op = out + b * sOutB + h * sOutH;
    __shared__ unsigned short tile[32][33];
    int r0 = blockIdx.y * 32, c0 = blockIdx.x * 32;
    int i = threadIdx.x >> 3;
    int j = (threadIdx.x & 7) * 4;
    ushort4 v = *reinterpret_cast<const ushort4*>(ip + (long)(r0 + i) * ldin + c0 + j);
    tile[i][j + 0] = v.x; tile[i][j + 1] = v.y; tile[i][j + 2] = v.z; tile[i][j + 3] = v.w;
    __syncthreads();
    ushort4 w;
    w.x = tile[j + 0][i]; w.y = tile[j + 1][i]; w.z = tile[j + 2][i]; w.w = tile[j + 3][i];
    *reinterpret_cast<ushort4*>(op + (long)(c0 + i) * ldout + r0 + j) = w;
}

// ---------------------------------------------------------------------------
// Pure-bf16 MFMA GEMM (r9-green): C = scale*A.Bt (+bias, relu), 128x128 tile,
// global_load_lds width-16 staging. Batched via blockIdx.z.
// ---------------------------------------------------------------------------
template<bool BIAS, bool RELU, bool OUTBF16>
__global__ __launch_bounds__(256) void gemm_bt(
    const unsigned short* __restrict__ A, int lda,
    const unsigned short* __restrict__ B, int ldb,
    void* __restrict__ Cv, int ldc,
    const float* __restrict__ bias, float scale, int K, int Hdiv,
    long sAb, long sAh, long sAz,
    long sBb, long sBh, long sBz,
    long sCb, long sCh, long sCz)
{
    const int m0 = blockIdx.y * 128;
    const int n0 = blockIdx.x * 128;
    int z  = blockIdx.z;
    int bb = z / Hdiv, hh = z % Hdiv;
    const unsigned short* Ab = A + bb * sAb + hh * sAh + (long)z * sAz;
    const unsigned short* Bb = B + bb * sBb + hh * sBh + (long)z * sBz;
    long coff = bb * sCb + hh * sCh + (long)z * sCz;

    __shared__ unsigned short As[128 * 32];
    __shared__ unsigned short Bs[128 * 32];

    const int tid  = threadIdx.x;
    const int lane = tid & 63;
    const int wave = tid >> 6;
    const int wm   = (wave >> 1) * 64;
    const int wn   = (wave & 1) * 64;
    const int lm   = lane & 15;
    const int kq   = (lane >> 4) * 8;

    f32x4 acc[4][4] = {};

    for (int k0 = 0; k0 < K; k0 += 32) {
#pragma unroll
        for (int it = 0; it < 2; ++it) {
            int id = tid + it * 256;
            int r  = id >> 2;
            int c8 = (id & 3) * 8;
            const unsigned short* gA = Ab + (long)(m0 + r) * lda + k0 + c8;
            const unsigned short* gB = Bb + (long)(n0 + r) * ldb + k0 + c8;
#if HAS_ASYNC
            unsigned short* lA = &As[(size_t)(it * 256 + wave * 64) * 8];
            unsigned short* lB = &Bs[(size_t)(it * 256 + wave * 64) * 8];
            __builtin_amdgcn_global_load_lds(
                (const __attribute__((address_space(1))) void*)gA,
                (__attribute__((address_space(3))) void*)lA, 16, 0, 0);
            __builtin_amdgcn_global_load_lds(
                (const __attribute__((address_space(1))) void*)gB,
                (__attribute__((address_space(3))) void*)lB, 16, 0, 0);
#else
            *reinterpret_cast<uint4*>(&As[(size_t)id * 8]) =
                *reinterpret_cast<const uint4*>(gA);
            *reinterpret_cast<uint4*>(&Bs[(size_t)id * 8]) =
                *reinterpret_cast<const uint4*>(gB);
#endif
        }
        __syncthreads();

        short8 af[4], bfr[4];
#pragma unroll
        for (int i = 0; i < 4; ++i)
            af[i] = *reinterpret_cast<const short8*>(&As[(wm + i * 16 + lm) * 32 + kq]);
#pragma unroll
        for (int j = 0; j < 4; ++j)
            bfr[j] = *reinterpret_cast<const short8*>(&Bs[(wn + j * 16 + lm) * 32 + kq]);
#pragma unroll
        for (int i = 0; i < 4; ++i)
#pragma unroll
            for (int j = 0; j < 4; ++j)
                acc[i][j] = __builtin_amdgcn_mfma_f32_16x16x32_bf16(af[i], bfr[j], acc[i][j], 0, 0, 0);
        __syncthreads();
    }

#pragma unroll
    for (int j = 0; j < 4; ++j) {
        int col  = n0 + wn + j * 16 + lm;
        float bv = 0.f;
        if (BIAS) bv = bias[col];
#pragma unroll
        for (int i = 0; i < 4; ++i) {
#pragma unroll
            for (int r = 0; r < 4; ++r) {
                int row = m0 + wm + i * 16 + (lane >> 4) * 4 + r;
                float v = acc[i][j][r] * scale + bv;
                if (RELU) v = fmaxf(v, 0.f);
                long idx = coff + (long)row * ldc + col;
                if (OUTBF16) reinterpret_cast<unsigned short*>(Cv)[idx] = f2b(v);
                else         reinterpret_cast<float*>(Cv)[idx] = v;
            }
        }
    }
}

// ---------------------------------------------------------------------------
// Fused flash attention (one bh x 64 q-rows per block; 4 waves x 16 rows).
//  Phase 1: S(16x512/wave, fp32 regs) = scale * Q.K^T  (K LDS-staged, 8 kc).
//  Softmax in regs: mask (k>q || rowmask) -> NEGV; all 512 keys computed so
//  fully-masked rows become uniform 1/512 automatically (r9 semantics).
//  Phase 2: O(16x256) = P.V  (V LDS-staged; P via per-wave LDS, A-layout).
// Layouts (m89-verified): A-frag A[m=lane&15][k=(lane>>4)*8+j];
//                         C/D col=lane&15, row=(lane>>4)*4+r.
// ---------------------------------------------------------------------------
__global__ __launch_bounds__(256) void flash_attn(
    const unsigned short* __restrict__ Qh,
    const unsigned short* __restrict__ Kh,
    const unsigned short* __restrict__ VhT,
    unsigned short* __restrict__ Vatt,
    const int* __restrict__ maskc, int bh0, float scale)
{
    const int tid  = threadIdx.x;
    const int lane = tid & 63;
    const int wave = tid >> 6;
    const int lm   = lane & 15;
    const int qg   = lane >> 4;
    const int kq   = qg * 8;

    const int z   = blockIdx.z;              // chunk-local bh
    const int b_l = z >> 2, h = z & 3;
    const int m0  = blockIdx.x * 64;         // q-tile base within seq
    const int wq0 = m0 + wave * 16;          // this wave's first q row
    const long qkbase = (long)b_l * SEQ * HD + (long)h * DM;
    const unsigned short* Aq = Qh + qkbase;
    const unsigned short* Ak = Kh + qkbase;
    const unsigned short* Av = VhT + (long)b_l * SEQ * HD + (long)h * SEQ * DM;
    unsigned short* Ov = Vatt + qkbase;
    const int bglob = (bh0 + z) >> 2;

    __shared__ unsigned short Ks[SEQ * 32];                 // 32 KiB (phase 1)
    __shared__ __align__(16) unsigned short Pw[4][16][40];  // 5 KiB, 80B rows

    f32x4 S[32] = {};

    // ---- Phase 1: S = Q.K^T over 8 k-chunks of 32 ----
    for (int kc = 0; kc < 8; ++kc) {
#pragma unroll
        for (int it = 0; it < 8; ++it) {
            int id = tid + it * 256;            // 0..2047 16B-chunks
            const unsigned short* g = Ak + (long)(id >> 2) * HD + kc * 32 + (id & 3) * 8;
#if HAS_ASYNC
            unsigned short* l = &Ks[(size_t)(it * 256 + wave * 64) * 8];
            __builtin_amdgcn_global_load_lds(
                (const __attribute__((address_space(1))) void*)g,
                (__attribute__((address_space(3))) void*)l, 16, 0, 0);
#else
            *reinterpret_cast<uint4*>(&Ks[(size_t)id * 8]) =
                *reinterpret_cast<const uint4*>(g);
#endif
        }
        short8 qf = *reinterpret_cast<const short8*>(
            Aq + (long)(wq0 + lm) * HD + kc * 32 + kq);
        __syncthreads();
#pragma unroll
        for (int nt = 0; nt < 32; ++nt) {
            short8 bf = *reinterpret_cast<const short8*>(&Ks[(nt * 16 + lm) * 32 + kq]);
            S[nt] = __builtin_amdgcn_mfma_f32_16x16x32_bf16(qf, bf, S[nt], 0, 0, 0);
        }
        __syncthreads();
    }

    // ---- Softmax in registers (per lane: 4 rows x 32 col-samples) ----
    int   qrow[4];
    bool  rowm[4];
    float mx[4], sm[4];
#pragma unroll
    for (int r = 0; r < 4; ++r) {
        int q = m0 + wave * 16 + qg * 4 + r;
        qrow[r] = q;
        rowm[r] = maskc[bglob * SEQ + q] != 0;
        mx[r] = -3.4e38f;
    }
#pragma unroll
    for (int nt = 0; nt < 32; ++nt) {
        int k = nt * 16 + lm;
#pragma unroll
        for (int r = 0; r < 4; ++r) {
            float v = S[nt][r] * scale;
            if (k > qrow[r] || rowm[r]) v = NEGV;
            S[nt][r] = v;
            mx[r] = fmaxf(mx[r], v);
        }
    }
#pragma unroll
    for (int r = 0; r < 4; ++r) {
#pragma unroll
        for (int off = 8; off >= 1; off >>= 1)
            mx[r] = fmaxf(mx[r], __shfl_xor(mx[r], off));
        sm[r] = 0.f;
    }
#pragma unroll
    for (int nt = 0; nt < 32; ++nt)
#pragma unroll
        for (int r = 0; r < 4; ++r) {
            float e = __expf(S[nt][r] - mx[r]);
            S[nt][r] = e;
            sm[r] += e;
        }
#pragma unroll
    for (int r = 0; r < 4; ++r) {
#pragma unroll
        for (int off = 8; off >= 1; off >>= 1)
            sm[r] += __shfl_xor(sm[r], off);
        sm[r] = 1.0f / sm[r];
    }
#pragma unroll
    for (int nt = 0; nt < 32; ++nt)
#pragma unroll
        for (int r = 0; r < 4; ++r) S[nt][r] *= sm[r];

    // ---- Phase 2: O = P.V over 16 key-chunks of 32 ----
    f32x4 O[16] = {};
    unsigned short* Vs = Ks;                 // reuse first 16 KiB
    for (int kc2 = 0; kc2 < 16; ++kc2) {
#pragma unroll
        for (int it = 0; it < 4; ++it) {
            int id = tid + it * 256;            // 0..1023 16B-chunks (256 d x 32 k)
            const unsigned short* g = Av + (long)(id >> 2) * SEQ + kc2 * 32 + (id & 3) * 8;
#if HAS_ASYNC
            unsigned short* l = &Vs[(size_t)(it * 256 + wave * 64) * 8];
            __builtin_amdgcn_global_load_lds(
                (const __attribute__((address_space(1))) void*)g,
                (__attribute__((address_space(3))) void*)l, 16, 0, 0);
#else
            *reinterpret_cast<uint4*>(&Vs[(size_t)id * 8]) =
                *reinterpret_cast<const uint4*>(g);
#endif
        }
        // P chunk (32 keys) C-layout -> per-wave LDS rows (A-layout source)
#pragma unroll
        for (int t = 0; t < 2; ++t) {
            int nt = kc2 * 2 + t;
#pragma unroll
            for (int r = 0; r < 4; ++r)
                Pw[wave][qg * 4 + r][t * 16 + lm] = f2b(S[nt][r]);
        }
        __syncthreads();
        short8 pf = *reinterpret_cast<const short8*>(&Pw[wave][lm][kq]);
#pragma unroll
        for (int nt2 = 0; nt2 < 16; ++nt2) {
            short8 vf = *reinterpret_cast<const short8*>(&Vs[(nt2 * 16 + lm) * 32 + kq]);
            O[nt2] = __builtin_amdgcn_mfma_f32_16x16x32_bf16(pf, vf, O[nt2], 0, 0, 0);
        }
        __syncthreads();
    }

    // ---- epilogue: O C-layout -> Vatt[b][q][h*256+d] bf16 ----
#pragma unroll
    for (int nt2 = 0; nt2 < 16; ++nt2) {
#pragma unroll
        for (int r = 0; r < 4; ++r) {
            int l = wq0 + qg * 4 + r;
            Ov[(long)l * HD + nt2 * 16 + lm] = f2b(O[nt2][r]);
        }
    }
}

// ---------------------------------------------------------------------------
// LN1: x = bf16 AttO + fp32 Q + fp32 pe  ->  fp32 Xf AND bf16 Xb
// ---------------------------------------------------------------------------
__global__ __launch_bounds__(256) void ln1_kernel(
    const unsigned short* __restrict__ AttO, const float* __restrict__ Q,
    const float* __restrict__ pe,
    const float* __restrict__ gamma, const float* __restrict__ beta,
    float* __restrict__ outf, unsigned short* __restrict__ outb)
{
    int row  = blockIdx.x * 4 + (threadIdx.x >> 6);
    int lane = threadIdx.x & 63;
    long base = (long)row * DM + lane * 4;
    ushort4 a = *reinterpret_cast<const ushort4*>(AttO + base);
    float4 qv = *reinterpret_cast<const float4*>(Q + base);
    float4 pv = *reinterpret_cast<const float4*>(pe + (base & PE_MASK));
    float x[4] = {b2f(a.x) + qv.x + pv.x, b2f(a.y) + qv.y + pv.y,
                  b2f(a.z) + qv.z + pv.z, b2f(a.w) + qv.w + pv.w};
    float s = x[0] + x[1] + x[2] + x[3];
#pragma unroll
    for (int off = 32; off > 0; off >>= 1) s += __shfl_xor(s, off);
    float mu = s * (1.0f / DM);
    float vs = 0.f;
#pragma unroll
    for (int t = 0; t < 4; ++t) { float d = x[t] - mu; vs += d * d; }
#pragma unroll
    for (int off = 32; off > 0; off >>= 1) vs += __shfl_xor(vs, off);
    float inv = rsqrtf(vs * (1.0f / DM) + 1e-5f);
    int d0 = lane * 4;
    float4 g = *reinterpret_cast<const float4*>(gamma + d0);
    float4 bt = *reinterpret_cast<const float4*>(beta + d0);
    float4 o;
    o.x = (x[0] - mu) * inv * g.x + bt.x;
    o.y = (x[1] - mu) * inv * g.y + bt.y;
    o.z = (x[2] - mu) * inv * g.z + bt.z;
    o.w = (x[3] - mu) * inv * g.w + bt.w;
    *reinterpret_cast<float4*>(outf + base) = o;
    ushort4 ob;
    ob.x = f2b(o.x); ob.y = f2b(o.y); ob.z = f2b(o.z); ob.w = f2b(o.w);
    *reinterpret_cast<ushort4*>(outb + base) = ob;
}

// ---------------------------------------------------------------------------
// LN2: x = fp32 F + fp32 X  ->  FP32 out
// ---------------------------------------------------------------------------
__global__ __launch_bounds__(256) void ln2_kernel(
    const float* __restrict__ F, const float* __restrict__ X,
    const float* __restrict__ gamma, const float* __restrict__ beta,
    float* __restrict__ out)
{
    int row  = blockIdx.x * 4 + (threadIdx.x >> 6);
    int lane = threadIdx.x & 63;
    long base = (long)row * DM + lane * 4;
    float4 a = *reinterpret_cast<const float4*>(F + base);
    float4 c = *reinterpret_cast<const float4*>(X + base);
    float x[4] = {a.x + c.x, a.y + c.y, a.z + c.z, a.w + c.w};
    float s = x[0] + x[1] + x[2] + x[3];
#pragma unroll
    for (int off = 32; off > 0; off >>= 1) s += __shfl_xor(s, off);
    float mu = s * (1.0f / DM);
    float vs = 0.f;
#pragma unroll
    for (int t = 0; t < 4; ++t) { float d = x[t] - mu; vs += d * d; }
#pragma unroll
    for (int off = 32; off > 0; off >>= 1) vs += __shfl_xor(vs, off);
    float inv = rsqrtf(vs * (1.0f / DM) + 1e-5f);
    int d0 = lane * 4;
    float4 g = *reinterpret_cast<const float4*>(gamma + d0);
    float4 bt = *reinterpret_cast<const float4*>(beta + d0);
    float4 o;
    o.x = (x[0] - mu) * inv * g.x + bt.x;
    o.y = (x[1] - mu) * inv * g.y + bt.y;
    o.z = (x[2] - mu) * inv * g.z + bt.z;
    o.w = (x[3] - mu) * inv * g.w + bt.w;
    *reinterpret_cast<float4*>(out + base) = o;
}

// ---------------------------------------------------------------------------
extern "C" void kernel_launch(void* const* d_in, const int* in_sizes, int n_in,
                              void* d_out, int out_size, void* d_ws, size_t ws_size,
                              hipStream_t stream)
{
    const float* Q  = (const float*)d_in[0];
    const float* Ki = (const float*)d_in[1];
    const float* Vi = (const float*)d_in[2];
    const unsigned char* mask_raw = (const unsigned char*)d_in[3];
    const float* pe = (const float*)d_in[4];
    const float* Wq = (const float*)d_in[5];
    const float* Wk = (const float*)d_in[6];
    const float* Wv = (const float*)d_in[7];
    const float* Wo = (const float*)d_in[8];
    const float* w1 = (const float*)d_in[9];
    const float* b1 = (const float*)d_in[10];
    const float* w2 = (const float*)d_in[11];
    const float* b2 = (const float*)d_in[12];
    const float* gamma = (const float*)d_in[13];
    const float* beta  = (const float*)d_in[14];
    float* out = (float*)d_out;

    const size_t MiB = 1048576;
    char* ws = (char*)d_ws;

    // ---- adaptive chunk size: footprint = 59 + max(5*CB, 24) MiB ----
    int CB = 1;
    for (int cb = 32; cb >= 1; cb >>= 1) {
        size_t scr_sz = (size_t)(5 * cb) * MiB;
        if (scr_sz < 24 * MiB) scr_sz = 24 * MiB;
        if ((59 * MiB + scr_sz) <= ws_size) { CB = cb; break; }
    }
    const int NCH = NB / CB;

    // ---- fixed low regions ----
    unsigned short* WqT  = (unsigned short*)(ws);                 // 512 KiB each
    unsigned short* WkT  = WqT + 262144;
    unsigned short* WvT  = WkT + 262144;
    unsigned short* WoT  = WvT + 262144;
    unsigned short* w1b  = (unsigned short*)(ws + 2 * MiB);       // 128 KiB
    unsigned short* w2b  = w1b + 65536;                           // 128 KiB
    int*            maskc = (int*)(ws + 2 * MiB + 262144);        // 64 KiB
    unsigned short* Qp   = (unsigned short*)(ws + 3 * MiB);       // 8 MiB bf16
    unsigned short* Kp   = (unsigned short*)(ws + 11 * MiB);      // 8 MiB
    unsigned short* Vp   = (unsigned short*)(ws + 19 * MiB);      // 8 MiB
    unsigned short* AttO = (unsigned short*)(ws + 27 * MiB);      // 8 MiB
    unsigned short* Xb   = (unsigned short*)(ws + 35 * MiB);      // 8 MiB
    float*          Xf   = (float*)(ws + 43 * MiB);               // 16 MiB
    char*           scr  = ws + 59 * MiB;
    // chunk scratch (CB MiB each)
    unsigned short* Qh   = (unsigned short*)(scr);
    unsigned short* Kh   = (unsigned short*)(scr + (size_t)CB * MiB);
    unsigned short* Vh   = (unsigned short*)(scr + (size_t)2 * CB * MiB);
    unsigned short* VhT  = (unsigned short*)(scr + (size_t)3 * CB * MiB);
    unsigned short* Vatt = (unsigned short*)(scr + (size_t)4 * CB * MiB);
    // tail aliases over scratch (chunk buffers dead by then)
    unsigned short* H1   = (unsigned short*)(scr);                // 8 MiB bf16
    float*          Ff   = (float*)(scr + 8 * MiB);               // 16 MiB fp32

    const float scale = (float)(1.0 / (16.0 + 1e-6));
    const long CROWS = (long)CB * SEQ;

    // 0. prep: mask, weight transposes/conversions, fused PE-add to bf16
    mask_canon<<<64, 256, 0, stream>>>(mask_raw, maskc);
    transpose_f2b<<<dim3(32, 8, 1), 256, 0, stream>>>(Wq, WqT, HD, DM);
    transpose_f2b<<<dim3(32, 8, 1), 256, 0, stream>>>(Wk, WkT, HD, DM);
    transpose_f2b<<<dim3(32, 8, 1), 256, 0, stream>>>(Wv, WvT, HD, DM);
    transpose_f2b<<<dim3(8, 32, 1), 256, 0, stream>>>(Wo, WoT, DM, HD);
    conv_f2b<<<64, 256, 0, stream>>>(w1, w1b);
    conv_f2b<<<64, 256, 0, stream>>>(w2, w2b);
    addpe_f2b<<<4096, 256, 0, stream>>>(Q,  pe, Qp);
    addpe_f2b<<<4096, 256, 0, stream>>>(Ki, pe, Kp);
    addpe_f2b<<<4096, 256, 0, stream>>>(Vi, pe, Vp);

    // 1. attention in NCH chunks of CB batches
    for (int c = 0; c < NCH; ++c) {
        const long r0   = (long)c * CROWS;
        const int  bh0  = c * CB * NH;
        const int  gy   = (int)(CROWS / 128);

        // projections: bf16 (X+pe) @ WxT -> bf16 Qh/Kh/Vh (chunk-local)
        gemm_bt<false, false, true><<<dim3(8, gy, 1), 256, 0, stream>>>(
            Qp + r0 * DM, DM, WqT, DM, Qh, HD, nullptr, 1.f, DM,
            1, 0,0,0, 0,0,0, 0,0,0);
        gemm_bt<false, false, true><<<dim3(8, gy, 1), 256, 0, stream>>>(
            Kp + r0 * DM, DM, WkT, DM, Kh, HD, nullptr, 1.f, DM,
            1, 0,0,0, 0,0,0, 0,0,0);
        gemm_bt<false, false, true><<<dim3(8, gy, 1), 256, 0, stream>>>(
            Vp + r0 * DM, DM, WvT, DM, Vh, HD, nullptr, 1.f, DM,
            1, 0,0,0, 0,0,0, 0,0,0);

        // per-head V transpose: VhT[bl][h][d][l] = Vh[bl][l][h*256+d]
        transpose_bf16<<<dim3(8, 16, CB * NH), 256, 0, stream>>>(
            Vh, VhT, HD, SEQ, (long)SEQ * HD, DM, (long)SEQ * HD, (long)SEQ * DM, NH);

        // fused attention: QK^T -> softmax -> PV  (no S materialization)
        flash_attn<<<dim3(8, 1, CB * NH), 256, 0, stream>>>(
            Qh, Kh, VhT, Vatt, maskc, bh0, scale);

        // output projection for this chunk -> AttO rows [r0, r0+CROWS)
        gemm_bt<false, false, true><<<dim3(2, gy, 1), 256, 0, stream>>>(
            Vatt, HD, WoT, HD, AttO + r0 * DM, DM, nullptr, 1.f, HD,
            1, 0,0,0, 0,0,0, 0,0,0);
    }

    // 2. LN1: X = LN(Q + pe + AttO) -> fp32 Xf + bf16 Xb
    ln1_kernel<<<4096, 256, 0, stream>>>(AttO, Q, pe, gamma, beta, Xf, Xb);

    // 3. FFN1: H1 = relu(Xb @ w1^T + b1) -> bf16
    gemm_bt<true, true, true><<<dim3(2, 128, 1), 256, 0, stream>>>(
        Xb, DM, w1b, DM, H1, DM, b1, 1.f, DM, 1, 0,0,0, 0,0,0, 0,0,0);
    // 4. FFN2: F = H1 @ w2^T + b2 -> fp32
    gemm_bt<true, false, false><<<dim3(2, 128, 1), 256, 0, stream>>>(
        H1, DM, w2b, DM, Ff, DM, b2, 1.f, DM, 1, 0,0,0, 0,0,0, 0,0,0);

    // 5. LN2: out = LN(F + X) -> FP32
    ln2_kernel<<<4096, 256, 0, stream>>>(Ff, Xf, gamma, beta, out);
}

// Round 11
// 388.729 us; speedup vs baseline: 4.9402x; 1.0891x over previous
//
#include <hip/hip_runtime.h>
#include <stdint.h>

// ---------------------------------------------------------------------------
// TransformerBlock: B=32, L=512, D=256, H=4.
// Inputs fp32 (dict order); OUTPUT fp32.
// bf16 MFMA GEMMs + fused flash attention with causal work-skip and
// XCD-affinity block swizzle. ws = 59 + 5*CB MiB (CB=32 -> single chunk).
// ---------------------------------------------------------------------------
#define SEQ   512
#define DM    256
#define NB    32
#define NH    4
#define HD    (NH * DM)           // 1024
#define PE_MASK (SEQ * DM - 1)    // 131071
#define NEGV  (-4294967295.0f)

typedef __attribute__((ext_vector_type(8))) short short8;   // 8 x bf16
typedef __attribute__((ext_vector_type(4))) float f32x4;    // MFMA accumulator

#if defined(__has_builtin)
#if __has_builtin(__builtin_amdgcn_global_load_lds)
#define HAS_ASYNC 1
#endif
#endif
#ifndef HAS_ASYNC
#define HAS_ASYNC 0
#endif

__device__ __forceinline__ float b2f(unsigned short u) {
    return __uint_as_float(((uint32_t)u) << 16);
}
__device__ __forceinline__ unsigned short f2b(float f) {
    uint32_t u = __float_as_uint(f);
    u += 0x7fffu + ((u >> 16) & 1u);   // RNE
    return (unsigned short)(u >> 16);
}

// ---------------------------------------------------------------------------
// Canonicalize mask to int32 (auto-detect uint8 / int32 / int64) — r7-green.
// ---------------------------------------------------------------------------
__global__ __launch_bounds__(256) void mask_canon(
    const unsigned char* __restrict__ raw, int* __restrict__ canon)
{
    __shared__ int enc_byte, enc_odd;
    int tid = threadIdx.x;
    if (tid == 0) { enc_byte = 0; enc_odd = 0; }
    __syncthreads();
    if (tid < 255 && raw[tid * 4 + 1]) atomicOr(&enc_byte, 1);
    if (tid < 128 && ((const int*)raw)[tid * 2 + 1]) atomicOr(&enc_odd, 1);
    __syncthreads();
    int i = blockIdx.x * 256 + tid;
    int v;
    if (enc_byte)      v = (raw[i] != 0);
    else if (enc_odd)  v = (((const int*)raw)[i] != 0);
    else               v = ((((const int*)raw)[i * 2] | ((const int*)raw)[i * 2 + 1]) != 0);
    canon[i] = v;
}

// ---------------------------------------------------------------------------
// addpe_f2b: out_bf16[i] = bf16(X[i] + pe[i mod 512*256]); 4 elems/thread.
// ---------------------------------------------------------------------------
__global__ __launch_bounds__(256) void addpe_f2b(
    const float* __restrict__ X, const float* __restrict__ pe,
    unsigned short* __restrict__ out)
{
    long i = (long)(blockIdx.x * 256 + threadIdx.x) * 4;
    float4 x = *reinterpret_cast<const float4*>(X + i);
    float4 p = *reinterpret_cast<const float4*>(pe + (i & PE_MASK));
    ushort4 o;
    o.x = f2b(x.x + p.x); o.y = f2b(x.y + p.y);
    o.z = f2b(x.z + p.z); o.w = f2b(x.w + p.w);
    *reinterpret_cast<ushort4*>(out + i) = o;
}

__global__ __launch_bounds__(256) void conv_f2b(
    const float* __restrict__ in, unsigned short* __restrict__ out)
{
    long i = (long)(blockIdx.x * 256 + threadIdx.x) * 4;
    float4 x = *reinterpret_cast<const float4*>(in + i);
    ushort4 o;
    o.x = f2b(x.x); o.y = f2b(x.y); o.z = f2b(x.z); o.w = f2b(x.w);
    *reinterpret_cast<ushort4*>(out + i) = o;
}

// ---------------------------------------------------------------------------
// Transpose fp32 in -> bf16 out: out[c][r] = bf16(in[r][c]); 32x32 tiles.
// ---------------------------------------------------------------------------
__global__ __launch_bounds__(256) void transpose_f2b(
    const float* __restrict__ in, unsigned short* __restrict__ out,
    int ldin, int ldout)
{
    __shared__ unsigned short tile[32][33];
    int r0 = blockIdx.y * 32, c0 = blockIdx.x * 32;
    int i = threadIdx.x >> 3;
    int j = (threadIdx.x & 7) * 4;
    float4 v = *reinterpret_cast<const float4*>(in + (long)(r0 + i) * ldin + c0 + j);
    tile[i][j + 0] = f2b(v.x); tile[i][j + 1] = f2b(v.y);
    tile[i][j + 2] = f2b(v.z); tile[i][j + 3] = f2b(v.w);
    __syncthreads();
    ushort4 w;
    w.x = tile[j + 0][i]; w.y = tile[j + 1][i]; w.z = tile[j + 2][i]; w.w = tile[j + 3][i];
    *reinterpret_cast<ushort4*>(out + (long)(c0 + i) * ldout + r0 + j) = w;
}

// ---------------------------------------------------------------------------
// Batched bf16 transpose (per-head V): out[c][r] = in[r][c]
// ---------------------------------------------------------------------------
__global__ __launch_bounds__(256) void transpose_bf16(
    const unsigned short* __restrict__ in, unsigned short* __restrict__ out,
    int ldin, int ldout, long sInB, long sInH, long sOutB, long sOutH, int Hdiv)
{
    int z = blockIdx.z; int b = z / Hdiv; int h = z % Hdiv;
    const unsigned short* ip = in + b * sInB + h * sInH;
    unsigned short* op = out + b * sOutB + h * sOutH;
    __shared__ unsigned short tile[32][33];
    int r0 = blockIdx.y * 32, c0 = blockIdx.x * 32;
    int i = threadIdx.x >> 3;
    int j = (threadIdx.x & 7) * 4;
    ushort4 v = *reinterpret_cast<const ushort4*>(ip + (long)(r0 + i) * ldin + c0 + j);
    tile[i][j + 0] = v.x; tile[i][j + 1] = v.y; tile[i][j + 2] = v.z; tile[i][j + 3] = v.w;
    __syncthreads();
    ushort4 w;
    w.x = tile[j + 0][i]; w.y = tile[j + 1][i]; w.z = tile[j + 2][i]; w.w = tile[j + 3][i];
    *reinterpret_cast<ushort4*>(op + (long)(c0 + i) * ldout + r0 + j) = w;
}

// ---------------------------------------------------------------------------
// Pure-bf16 MFMA GEMM (r9-green): C = scale*A.Bt (+bias, relu), 128x128 tile,
// global_load_lds width-16 staging. Batched via blockIdx.z.
// ---------------------------------------------------------------------------
template<bool BIAS, bool RELU, bool OUTBF16>
__global__ __launch_bounds__(256) void gemm_bt(
    const unsigned short* __restrict__ A, int lda,
    const unsigned short* __restrict__ B, int ldb,
    void* __restrict__ Cv, int ldc,
    const float* __restrict__ bias, float scale, int K, int Hdiv,
    long sAb, long sAh, long sAz,
    long sBb, long sBh, long sBz,
    long sCb, long sCh, long sCz)
{
    const int m0 = blockIdx.y * 128;
    const int n0 = blockIdx.x * 128;
    int z  = blockIdx.z;
    int bb = z / Hdiv, hh = z % Hdiv;
    const unsigned short* Ab = A + bb * sAb + hh * sAh + (long)z * sAz;
    const unsigned short* Bb = B + bb * sBb + hh * sBh + (long)z * sBz;
    long coff = bb * sCb + hh * sCh + (long)z * sCz;

    __shared__ unsigned short As[128 * 32];
    __shared__ unsigned short Bs[128 * 32];

    const int tid  = threadIdx.x;
    const int lane = tid & 63;
    const int wave = tid >> 6;
    const int wm   = (wave >> 1) * 64;
    const int wn   = (wave & 1) * 64;
    const int lm   = lane & 15;
    const int kq   = (lane >> 4) * 8;

    f32x4 acc[4][4] = {};

    for (int k0 = 0; k0 < K; k0 += 32) {
#pragma unroll
        for (int it = 0; it < 2; ++it) {
            int id = tid + it * 256;
            int r  = id >> 2;
            int c8 = (id & 3) * 8;
            const unsigned short* gA = Ab + (long)(m0 + r) * lda + k0 + c8;
            const unsigned short* gB = Bb + (long)(n0 + r) * ldb + k0 + c8;
#if HAS_ASYNC
            unsigned short* lA = &As[(size_t)(it * 256 + wave * 64) * 8];
            unsigned short* lB = &Bs[(size_t)(it * 256 + wave * 64) * 8];
            __builtin_amdgcn_global_load_lds(
                (const __attribute__((address_space(1))) void*)gA,
                (__attribute__((address_space(3))) void*)lA, 16, 0, 0);
            __builtin_amdgcn_global_load_lds(
                (const __attribute__((address_space(1))) void*)gB,
                (__attribute__((address_space(3))) void*)lB, 16, 0, 0);
#else
            *reinterpret_cast<uint4*>(&As[(size_t)id * 8]) =
                *reinterpret_cast<const uint4*>(gA);
            *reinterpret_cast<uint4*>(&Bs[(size_t)id * 8]) =
                *reinterpret_cast<const uint4*>(gB);
#endif
        }
        __syncthreads();

        short8 af[4], bfr[4];
#pragma unroll
        for (int i = 0; i < 4; ++i)
            af[i] = *reinterpret_cast<const short8*>(&As[(wm + i * 16 + lm) * 32 + kq]);
#pragma unroll
        for (int j = 0; j < 4; ++j)
            bfr[j] = *reinterpret_cast<const short8*>(&Bs[(wn + j * 16 + lm) * 32 + kq]);
#pragma unroll
        for (int i = 0; i < 4; ++i)
#pragma unroll
            for (int j = 0; j < 4; ++j)
                acc[i][j] = __builtin_amdgcn_mfma_f32_16x16x32_bf16(af[i], bfr[j], acc[i][j], 0, 0, 0);
        __syncthreads();
    }

#pragma unroll
    for (int j = 0; j < 4; ++j) {
        int col  = n0 + wn + j * 16 + lm;
        float bv = 0.f;
        if (BIAS) bv = bias[col];
#pragma unroll
        for (int i = 0; i < 4; ++i) {
#pragma unroll
            for (int r = 0; r < 4; ++r) {
                int row = m0 + wm + i * 16 + (lane >> 4) * 4 + r;
                float v = acc[i][j][r] * scale + bv;
                if (RELU) v = fmaxf(v, 0.f);
                long idx = coff + (long)row * ldc + col;
                if (OUTBF16) reinterpret_cast<unsigned short*>(Cv)[idx] = f2b(v);
                else         reinterpret_cast<float*>(Cv)[idx] = v;
            }
        }
    }
}

// ---------------------------------------------------------------------------
// Fused flash attention. Linear grid of 8*nbh blocks, XCD-affinity swizzle:
//   z = L % nbh (bh), qt = L / nbh  ->  all q-tiles of a bh share L%8 (XCD).
// Phase 1 (causal-limited): stage K rows [0, (qt+1)*64); per-wave MFMA tile
//   bound NT = m0/16 + wave + 1 (skipped tiles stay 0 -> masked downstream;
//   pad-masked rows still get uniform 1/512 since masking overwrites S).
// Phase 2: full 512 keys (pad-masked rows attend to everything).
// Layouts m89-verified.
// ---------------------------------------------------------------------------
__global__ __launch_bounds__(256) void flash_attn(
    const unsigned short* __restrict__ Qh,
    const unsigned short* __restrict__ Kh,
    const unsigned short* __restrict__ VhT,
    unsigned short* __restrict__ Vatt,
    const int* __restrict__ maskc, int bh0, float scale, int nbh)
{
    const int tid  = threadIdx.x;
    const int lane = tid & 63;
    const int wave = tid >> 6;
    const int lm   = lane & 15;
    const int qg   = lane >> 4;
    const int kq   = qg * 8;

    const int L   = blockIdx.x;
    const int z   = L % nbh;                 // chunk-local bh
    const int qt  = L / nbh;                 // q-tile 0..7
    const int b_l = z >> 2, h = z & 3;
    const int m0  = qt * 64;
    const int wq0 = m0 + wave * 16;
    const long qkbase = (long)b_l * SEQ * HD + (long)h * DM;
    const unsigned short* Aq = Qh + qkbase;
    const unsigned short* Ak = Kh + qkbase;
    const unsigned short* Av = VhT + (long)b_l * SEQ * HD + (long)h * SEQ * DM;
    unsigned short* Ov = Vatt + qkbase;
    const int bglob = (bh0 + z) >> 2;

    __shared__ unsigned short Ks[SEQ * 32];                 // 32 KiB
    __shared__ __align__(16) unsigned short Pw[4][16][40];  // 5 KiB

    f32x4 S[32] = {};
    const int NT = (m0 >> 4) + wave + 1;     // causal tile bound (wave-uniform)

    // ---- Phase 1: S = Q.K^T over 8 d-chunks of 32; K rows [0,(qt+1)*64) ----
    for (int kc = 0; kc < 8; ++kc) {
        for (int it = 0; it <= qt; ++it) {   // block-uniform causal staging
            int id = tid + it * 256;         // covers rows [it*64, it*64+64)
            const unsigned short* g = Ak + (long)(id >> 2) * HD + kc * 32 + (id & 3) * 8;
#if HAS_ASYNC
            unsigned short* l = &Ks[(size_t)(it * 256 + wave * 64) * 8];
            __builtin_amdgcn_global_load_lds(
                (const __attribute__((address_space(1))) void*)g,
                (__attribute__((address_space(3))) void*)l, 16, 0, 0);
#else
            *reinterpret_cast<uint4*>(&Ks[(size_t)id * 8]) =
                *reinterpret_cast<const uint4*>(g);
#endif
        }
        short8 qf = *reinterpret_cast<const short8*>(
            Aq + (long)(wq0 + lm) * HD + kc * 32 + kq);
        __syncthreads();
#pragma unroll
        for (int nt = 0; nt < 32; ++nt) {
            if (nt < NT) {
                short8 bf = *reinterpret_cast<const short8*>(&Ks[(nt * 16 + lm) * 32 + kq]);
                S[nt] = __builtin_amdgcn_mfma_f32_16x16x32_bf16(qf, bf, S[nt], 0, 0, 0);
            }
        }
        __syncthreads();
    }

    // ---- Softmax in registers ----
    int   qrow[4];
    bool  rowm[4];
    float mx[4], sm[4];
#pragma unroll
    for (int r = 0; r < 4; ++r) {
        int q = wq0 + qg * 4 + r;
        qrow[r] = q;
        rowm[r] = maskc[bglob * SEQ + q] != 0;
        mx[r] = -3.4e38f;
    }
#pragma unroll
    for (int nt = 0; nt < 32; ++nt) {
        int k = nt * 16 + lm;
#pragma unroll
        for (int r = 0; r < 4; ++r) {
            float v = S[nt][r] * scale;
            if (k > qrow[r] || rowm[r]) v = NEGV;
            S[nt][r] = v;
            mx[r] = fmaxf(mx[r], v);
        }
    }
#pragma unroll
    for (int r = 0; r < 4; ++r) {
#pragma unroll
        for (int off = 8; off >= 1; off >>= 1)
            mx[r] = fmaxf(mx[r], __shfl_xor(mx[r], off));
        sm[r] = 0.f;
    }
#pragma unroll
    for (int nt = 0; nt < 32; ++nt)
#pragma unroll
        for (int r = 0; r < 4; ++r) {
            float e = __expf(S[nt][r] - mx[r]);
            S[nt][r] = e;
            sm[r] += e;
        }
#pragma unroll
    for (int r = 0; r < 4; ++r) {
#pragma unroll
        for (int off = 8; off >= 1; off >>= 1)
            sm[r] += __shfl_xor(sm[r], off);
        sm[r] = 1.0f / sm[r];
    }
#pragma unroll
    for (int nt = 0; nt < 32; ++nt)
#pragma unroll
        for (int r = 0; r < 4; ++r) S[nt][r] *= sm[r];

    // ---- Phase 2: O = P.V over 16 key-chunks of 32 (full 512 keys) ----
    f32x4 O[16] = {};
    unsigned short* Vs = Ks;
    for (int kc2 = 0; kc2 < 16; ++kc2) {
#pragma unroll
        for (int it = 0; it < 4; ++it) {
            int id = tid + it * 256;            // 256 d-rows x 32 keys
            const unsigned short* g = Av + (long)(id >> 2) * SEQ + kc2 * 32 + (id & 3) * 8;
#if HAS_ASYNC
            unsigned short* l = &Vs[(size_t)(it * 256 + wave * 64) * 8];
            __builtin_amdgcn_global_load_lds(
                (const __attribute__((address_space(1))) void*)g,
                (__attribute__((address_space(3))) void*)l, 16, 0, 0);
#else
            *reinterpret_cast<uint4*>(&Vs[(size_t)id * 8]) =
                *reinterpret_cast<const uint4*>(g);
#endif
        }
#pragma unroll
        for (int t = 0; t < 2; ++t) {
            int nt = kc2 * 2 + t;
#pragma unroll
            for (int r = 0; r < 4; ++r)
                Pw[wave][qg * 4 + r][t * 16 + lm] = f2b(S[nt][r]);
        }
        __syncthreads();
        short8 pf = *reinterpret_cast<const short8*>(&Pw[wave][lm][kq]);
#pragma unroll
        for (int nt2 = 0; nt2 < 16; ++nt2) {
            short8 vf = *reinterpret_cast<const short8*>(&Vs[(nt2 * 16 + lm) * 32 + kq]);
            O[nt2] = __builtin_amdgcn_mfma_f32_16x16x32_bf16(pf, vf, O[nt2], 0, 0, 0);
        }
        __syncthreads();
    }

    // ---- epilogue ----
#pragma unroll
    for (int nt2 = 0; nt2 < 16; ++nt2) {
#pragma unroll
        for (int r = 0; r < 4; ++r) {
            int l = wq0 + qg * 4 + r;
            Ov[(long)l * HD + nt2 * 16 + lm] = f2b(O[nt2][r]);
        }
    }
}

// ---------------------------------------------------------------------------
// LN1: x = bf16 AttO + fp32 Q + fp32 pe  ->  fp32 Xf AND bf16 Xb
// ---------------------------------------------------------------------------
__global__ __launch_bounds__(256) void ln1_kernel(
    const unsigned short* __restrict__ AttO, const float* __restrict__ Q,
    const float* __restrict__ pe,
    const float* __restrict__ gamma, const float* __restrict__ beta,
    float* __restrict__ outf, unsigned short* __restrict__ outb)
{
    int row  = blockIdx.x * 4 + (threadIdx.x >> 6);
    int lane = threadIdx.x & 63;
    long base = (long)row * DM + lane * 4;
    ushort4 a = *reinterpret_cast<const ushort4*>(AttO + base);
    float4 qv = *reinterpret_cast<const float4*>(Q + base);
    float4 pv = *reinterpret_cast<const float4*>(pe + (base & PE_MASK));
    float x[4] = {b2f(a.x) + qv.x + pv.x, b2f(a.y) + qv.y + pv.y,
                  b2f(a.z) + qv.z + pv.z, b2f(a.w) + qv.w + pv.w};
    float s = x[0] + x[1] + x[2] + x[3];
#pragma unroll
    for (int off = 32; off > 0; off >>= 1) s += __shfl_xor(s, off);
    float mu = s * (1.0f / DM);
    float vs = 0.f;
#pragma unroll
    for (int t = 0; t < 4; ++t) { float d = x[t] - mu; vs += d * d; }
#pragma unroll
    for (int off = 32; off > 0; off >>= 1) vs += __shfl_xor(vs, off);
    float inv = rsqrtf(vs * (1.0f / DM) + 1e-5f);
    int d0 = lane * 4;
    float4 g = *reinterpret_cast<const float4*>(gamma + d0);
    float4 bt = *reinterpret_cast<const float4*>(beta + d0);
    float4 o;
    o.x = (x[0] - mu) * inv * g.x + bt.x;
    o.y = (x[1] - mu) * inv * g.y + bt.y;
    o.z = (x[2] - mu) * inv * g.z + bt.z;
    o.w = (x[3] - mu) * inv * g.w + bt.w;
    *reinterpret_cast<float4*>(outf + base) = o;
    ushort4 ob;
    ob.x = f2b(o.x); ob.y = f2b(o.y); ob.z = f2b(o.z); ob.w = f2b(o.w);
    *reinterpret_cast<ushort4*>(outb + base) = ob;
}

// ---------------------------------------------------------------------------
// LN2: x = fp32 F + fp32 X  ->  FP32 out
// ---------------------------------------------------------------------------
__global__ __launch_bounds__(256) void ln2_kernel(
    const float* __restrict__ F, const float* __restrict__ X,
    const float* __restrict__ gamma, const float* __restrict__ beta,
    float* __restrict__ out)
{
    int row  = blockIdx.x * 4 + (threadIdx.x >> 6);
    int lane = threadIdx.x & 63;
    long base = (long)row * DM + lane * 4;
    float4 a = *reinterpret_cast<const float4*>(F + base);
    float4 c = *reinterpret_cast<const float4*>(X + base);
    float x[4] = {a.x + c.x, a.y + c.y, a.z + c.z, a.w + c.w};
    float s = x[0] + x[1] + x[2] + x[3];
#pragma unroll
    for (int off = 32; off > 0; off >>= 1) s += __shfl_xor(s, off);
    float mu = s * (1.0f / DM);
    float vs = 0.f;
#pragma unroll
    for (int t = 0; t < 4; ++t) { float d = x[t] - mu; vs += d * d; }
#pragma unroll
    for (int off = 32; off > 0; off >>= 1) vs += __shfl_xor(vs, off);
    float inv = rsqrtf(vs * (1.0f / DM) + 1e-5f);
    int d0 = lane * 4;
    float4 g = *reinterpret_cast<const float4*>(gamma + d0);
    float4 bt = *reinterpret_cast<const float4*>(beta + d0);
    float4 o;
    o.x = (x[0] - mu) * inv * g.x + bt.x;
    o.y = (x[1] - mu) * inv * g.y + bt.y;
    o.z = (x[2] - mu) * inv * g.z + bt.z;
    o.w = (x[3] - mu) * inv * g.w + bt.w;
    *reinterpret_cast<float4*>(out + base) = o;
}

// ---------------------------------------------------------------------------
extern "C" void kernel_launch(void* const* d_in, const int* in_sizes, int n_in,
                              void* d_out, int out_size, void* d_ws, size_t ws_size,
                              hipStream_t stream)
{
    const float* Q  = (const float*)d_in[0];
    const float* Ki = (const float*)d_in[1];
    const float* Vi = (const float*)d_in[2];
    const unsigned char* mask_raw = (const unsigned char*)d_in[3];
    const float* pe = (const float*)d_in[4];
    const float* Wq = (const float*)d_in[5];
    const float* Wk = (const float*)d_in[6];
    const float* Wv = (const float*)d_in[7];
    const float* Wo = (const float*)d_in[8];
    const float* w1 = (const float*)d_in[9];
    const float* b1 = (const float*)d_in[10];
    const float* w2 = (const float*)d_in[11];
    const float* b2 = (const float*)d_in[12];
    const float* gamma = (const float*)d_in[13];
    const float* beta  = (const float*)d_in[14];
    float* out = (float*)d_out;

    const size_t MiB = 1048576;
    char* ws = (char*)d_ws;

    // ---- adaptive chunk size: footprint = 59 + max(5*CB, 24) MiB ----
    int CB = 1;
    for (int cb = 32; cb >= 1; cb >>= 1) {
        size_t scr_sz = (size_t)(5 * cb) * MiB;
        if (scr_sz < 24 * MiB) scr_sz = 24 * MiB;
        if ((59 * MiB + scr_sz) <= ws_size) { CB = cb; break; }
    }
    const int NCH = NB / CB;

    // ---- fixed low regions ----
    unsigned short* WqT  = (unsigned short*)(ws);                 // 512 KiB each
    unsigned short* WkT  = WqT + 262144;
    unsigned short* WvT  = WkT + 262144;
    unsigned short* WoT  = WvT + 262144;
    unsigned short* w1b  = (unsigned short*)(ws + 2 * MiB);       // 128 KiB
    unsigned short* w2b  = w1b + 65536;                           // 128 KiB
    int*            maskc = (int*)(ws + 2 * MiB + 262144);        // 64 KiB
    unsigned short* Qp   = (unsigned short*)(ws + 3 * MiB);       // 8 MiB bf16
    unsigned short* Kp   = (unsigned short*)(ws + 11 * MiB);      // 8 MiB
    unsigned short* Vp   = (unsigned short*)(ws + 19 * MiB);      // 8 MiB
    unsigned short* AttO = (unsigned short*)(ws + 27 * MiB);      // 8 MiB
    unsigned short* Xb   = (unsigned short*)(ws + 35 * MiB);      // 8 MiB
    float*          Xf   = (float*)(ws + 43 * MiB);               // 16 MiB
    char*           scr  = ws + 59 * MiB;
    // chunk scratch (CB MiB each)
    unsigned short* Qh   = (unsigned short*)(scr);
    unsigned short* Kh   = (unsigned short*)(scr + (size_t)CB * MiB);
    unsigned short* Vh   = (unsigned short*)(scr + (size_t)2 * CB * MiB);
    unsigned short* VhT  = (unsigned short*)(scr + (size_t)3 * CB * MiB);
    unsigned short* Vatt = (unsigned short*)(scr + (size_t)4 * CB * MiB);
    // tail aliases over scratch (chunk buffers dead by then)
    unsigned short* H1   = (unsigned short*)(scr);                // 8 MiB bf16
    float*          Ff   = (float*)(scr + 8 * MiB);               // 16 MiB fp32

    const float scale = (float)(1.0 / (16.0 + 1e-6));
    const long CROWS = (long)CB * SEQ;
    const long CBELT = (long)CB * MiB / 2;     // chunk-buffer stride, elements

    // 0. prep: mask, weight transposes/conversions, fused PE-add to bf16
    mask_canon<<<64, 256, 0, stream>>>(mask_raw, maskc);
    transpose_f2b<<<dim3(32, 8, 1), 256, 0, stream>>>(Wq, WqT, HD, DM);
    transpose_f2b<<<dim3(32, 8, 1), 256, 0, stream>>>(Wk, WkT, HD, DM);
    transpose_f2b<<<dim3(32, 8, 1), 256, 0, stream>>>(Wv, WvT, HD, DM);
    transpose_f2b<<<dim3(8, 32, 1), 256, 0, stream>>>(Wo, WoT, DM, HD);
    conv_f2b<<<64, 256, 0, stream>>>(w1, w1b);
    conv_f2b<<<64, 256, 0, stream>>>(w2, w2b);
    addpe_f2b<<<4096, 256, 0, stream>>>(Q,  pe, Qp);
    addpe_f2b<<<4096, 256, 0, stream>>>(Ki, pe, Kp);
    addpe_f2b<<<4096, 256, 0, stream>>>(Vi, pe, Vp);

    // 1. attention in NCH chunks of CB batches
    for (int c = 0; c < NCH; ++c) {
        const long r0   = (long)c * CROWS;
        const int  bh0  = c * CB * NH;
        const int  gy   = (int)(CROWS / 128);
        const int  nbh  = CB * NH;

        // all 3 projections in ONE dispatch (z=0:Q, 1:K, 2:V)
        // A: Qp/Kp/Vp are 4Mi elements apart; B: WqT/WkT/WvT 256Ki apart;
        // C: Qh/Kh/Vh are CBELT apart.
        gemm_bt<false, false, true><<<dim3(8, gy, 3), 256, 0, stream>>>(
            Qp + r0 * DM, DM, WqT, DM, Qh, HD, nullptr, 1.f, DM,
            1, 4194304, 0, 0, 262144, 0, 0, CBELT, 0, 0);

        // per-head V transpose: VhT[bl][h][d][l] = Vh[bl][l][h*256+d]
        transpose_bf16<<<dim3(8, 16, CB * NH), 256, 0, stream>>>(
            Vh, VhT, HD, SEQ, (long)SEQ * HD, DM, (long)SEQ * HD, (long)SEQ * DM, NH);

        // fused attention (causal-skip + XCD swizzle)
        flash_attn<<<dim3(8 * nbh, 1, 1), 256, 0, stream>>>(
            Qh, Kh, VhT, Vatt, maskc, bh0, scale, nbh);

        // output projection for this chunk -> AttO rows [r0, r0+CROWS)
        gemm_bt<false, false, true><<<dim3(2, gy, 1), 256, 0, stream>>>(
            Vatt, HD, WoT, HD, AttO + r0 * DM, DM, nullptr, 1.f, HD,
            1, 0,0,0, 0,0,0, 0,0,0);
    }

    // 2. LN1: X = LN(Q + pe + AttO) -> fp32 Xf + bf16 Xb
    ln1_kernel<<<4096, 256, 0, stream>>>(AttO, Q, pe, gamma, beta, Xf, Xb);

    // 3. FFN1: H1 = relu(Xb @ w1^T + b1) -> bf16
    gemm_bt<true, true, true><<<dim3(2, 128, 1), 256, 0, stream>>>(
        Xb, DM, w1b, DM, H1, DM, b1, 1.f, DM, 1, 0,0,0, 0,0,0, 0,0,0);
    // 4. FFN2: F = H1 @ w2^T + b2 -> fp32
    gemm_bt<true, false, false><<<dim3(2, 128, 1), 256, 0, stream>>>(
        H1, DM, w2b, DM, Ff, DM, b2, 1.f, DM, 1, 0,0,0, 0,0,0, 0,0,0);

    // 5. LN2: out = LN(F + X) -> FP32
    ln2_kernel<<<4096, 256, 0, stream>>>(Ff, Xf, gamma, beta, out);
}

// Round 12
// 387.073 us; speedup vs baseline: 4.9613x; 1.0043x over previous
//
#include <hip/hip_runtime.h>
#include <stdint.h>

// ---------------------------------------------------------------------------
// TransformerBlock: B=32, L=512, D=256, H=4.
// Inputs fp32 (dict order); OUTPUT fp32.
// bf16 MFMA GEMMs + fused flash attention:
//   - balanced XCD-affinity swizzle (all q-tiles of a bh on one XCD, qt
//     fast-varying in dispatch order for load balance)
//   - causal staging+MFMA skip in phase 1
//   - phase-2 V double-buffer (1 barrier/iter, staging overlaps MFMA)
// ws = 59 + 5*CB MiB (CB=32 -> single chunk at ws=256MiB).
// ---------------------------------------------------------------------------
#define SEQ   512
#define DM    256
#define NB    32
#define NH    4
#define HD    (NH * DM)           // 1024
#define PE_MASK (SEQ * DM - 1)    // 131071
#define NEGV  (-4294967295.0f)

typedef __attribute__((ext_vector_type(8))) short short8;   // 8 x bf16
typedef __attribute__((ext_vector_type(4))) float f32x4;    // MFMA accumulator

#if defined(__has_builtin)
#if __has_builtin(__builtin_amdgcn_global_load_lds)
#define HAS_ASYNC 1
#endif
#endif
#ifndef HAS_ASYNC
#define HAS_ASYNC 0
#endif

__device__ __forceinline__ float b2f(unsigned short u) {
    return __uint_as_float(((uint32_t)u) << 16);
}
__device__ __forceinline__ unsigned short f2b(float f) {
    uint32_t u = __float_as_uint(f);
    u += 0x7fffu + ((u >> 16) & 1u);   // RNE
    return (unsigned short)(u >> 16);
}

// ---------------------------------------------------------------------------
// Canonicalize mask to int32 (auto-detect uint8 / int32 / int64) — r7-green.
// ---------------------------------------------------------------------------
__global__ __launch_bounds__(256) void mask_canon(
    const unsigned char* __restrict__ raw, int* __restrict__ canon)
{
    __shared__ int enc_byte, enc_odd;
    int tid = threadIdx.x;
    if (tid == 0) { enc_byte = 0; enc_odd = 0; }
    __syncthreads();
    if (tid < 255 && raw[tid * 4 + 1]) atomicOr(&enc_byte, 1);
    if (tid < 128 && ((const int*)raw)[tid * 2 + 1]) atomicOr(&enc_odd, 1);
    __syncthreads();
    int i = blockIdx.x * 256 + tid;
    int v;
    if (enc_byte)      v = (raw[i] != 0);
    else if (enc_odd)  v = (((const int*)raw)[i] != 0);
    else               v = ((((const int*)raw)[i * 2] | ((const int*)raw)[i * 2 + 1]) != 0);
    canon[i] = v;
}

// ---------------------------------------------------------------------------
// addpe3: Q/K/V + pe -> bf16, one dispatch (seg = blk>>12).
// ---------------------------------------------------------------------------
__global__ __launch_bounds__(256) void addpe3(
    const float* __restrict__ Q, const float* __restrict__ K,
    const float* __restrict__ V, const float* __restrict__ pe,
    unsigned short* __restrict__ Qp, unsigned short* __restrict__ Kp,
    unsigned short* __restrict__ Vp)
{
    int blk = blockIdx.x;                  // 0..12287
    int seg = blk >> 12;
    const float* X = (seg == 0) ? Q : (seg == 1) ? K : V;
    unsigned short* O = (seg == 0) ? Qp : (seg == 1) ? Kp : Vp;
    long i = (long)((blk & 4095) * 256 + threadIdx.x) * 4;
    float4 x = *reinterpret_cast<const float4*>(X + i);
    float4 p = *reinterpret_cast<const float4*>(pe + (i & PE_MASK));
    ushort4 o;
    o.x = f2b(x.x + p.x); o.y = f2b(x.y + p.y);
    o.z = f2b(x.z + p.z); o.w = f2b(x.w + p.w);
    *reinterpret_cast<ushort4*>(O + i) = o;
}

// ---------------------------------------------------------------------------
// conv2: w1,w2 fp32 -> bf16, one dispatch (128 blocks, seg = blk>>6).
// ---------------------------------------------------------------------------
__global__ __launch_bounds__(256) void conv2(
    const float* __restrict__ w1, const float* __restrict__ w2,
    unsigned short* __restrict__ o1, unsigned short* __restrict__ o2)
{
    int blk = blockIdx.x;
    const float* in = (blk < 64) ? w1 : w2;
    unsigned short* out = (blk < 64) ? o1 : o2;
    long i = (long)((blk & 63) * 256 + threadIdx.x) * 4;
    float4 x = *reinterpret_cast<const float4*>(in + i);
    ushort4 o;
    o.x = f2b(x.x); o.y = f2b(x.y); o.z = f2b(x.z); o.w = f2b(x.w);
    *reinterpret_cast<ushort4*>(out + i) = o;
}

// ---------------------------------------------------------------------------
// Transpose fp32 -> bf16: out[c][r] = bf16(in[r][c]); 32x32 tiles.
// z selects among 3 same-shape inputs (Wq/Wk/Wv), out spaced by outStride.
// ---------------------------------------------------------------------------
__global__ __launch_bounds__(256) void transpose_f2b3(
    const float* __restrict__ in0, const float* __restrict__ in1,
    const float* __restrict__ in2, unsigned short* __restrict__ out,
    int ldin, int ldout, long outStride)
{
    int z = blockIdx.z;
    const float* in = (z == 0) ? in0 : (z == 1) ? in1 : in2;
    unsigned short* op = out + z * outStride;
    __shared__ unsigned short tile[32][33];
    int r0 = blockIdx.y * 32, c0 = blockIdx.x * 32;
    int i = threadIdx.x >> 3;
    int j = (threadIdx.x & 7) * 4;
    float4 v = *reinterpret_cast<const float4*>(in + (long)(r0 + i) * ldin + c0 + j);
    tile[i][j + 0] = f2b(v.x); tile[i][j + 1] = f2b(v.y);
    tile[i][j + 2] = f2b(v.z); tile[i][j + 3] = f2b(v.w);
    __syncthreads();
    ushort4 w;
    w.x = tile[j + 0][i]; w.y = tile[j + 1][i]; w.z = tile[j + 2][i]; w.w = tile[j + 3][i];
    *reinterpret_cast<ushort4*>(op + (long)(c0 + i) * ldout + r0 + j) = w;
}

__global__ __launch_bounds__(256) void transpose_f2b(
    const float* __restrict__ in, unsigned short* __restrict__ out,
    int ldin, int ldout)
{
    __shared__ unsigned short tile[32][33];
    int r0 = blockIdx.y * 32, c0 = blockIdx.x * 32;
    int i = threadIdx.x >> 3;
    int j = (threadIdx.x & 7) * 4;
    float4 v = *reinterpret_cast<const float4*>(in + (long)(r0 + i) * ldin + c0 + j);
    tile[i][j + 0] = f2b(v.x); tile[i][j + 1] = f2b(v.y);
    tile[i][j + 2] = f2b(v.z); tile[i][j + 3] = f2b(v.w);
    __syncthreads();
    ushort4 w;
    w.x = tile[j + 0][i]; w.y = tile[j + 1][i]; w.z = tile[j + 2][i]; w.w = tile[j + 3][i];
    *reinterpret_cast<ushort4*>(out + (long)(c0 + i) * ldout + r0 + j) = w;
}

// ---------------------------------------------------------------------------
// Batched bf16 transpose (per-head V): out[c][r] = in[r][c]
// ---------------------------------------------------------------------------
__global__ __launch_bounds__(256) void transpose_bf16(
    const unsigned short* __restrict__ in, unsigned short* __restrict__ out,
    int ldin, int ldout, long sInB, long sInH, long sOutB, long sOutH, int Hdiv)
{
    int z = blockIdx.z; int b = z / Hdiv; int h = z % Hdiv;
    const unsigned short* ip = in + b * sInB + h * sInH;
    unsigned short* op = out + b * sOutB + h * sOutH;
    __shared__ unsigned short tile[32][33];
    int r0 = blockIdx.y * 32, c0 = blockIdx.x * 32;
    int i = threadIdx.x >> 3;
    int j = (threadIdx.x & 7) * 4;
    ushort4 v = *reinterpret_cast<const ushort4*>(ip + (long)(r0 + i) * ldin + c0 + j);
    tile[i][j + 0] = v.x; tile[i][j + 1] = v.y; tile[i][j + 2] = v.z; tile[i][j + 3] = v.w;
    __syncthreads();
    ushort4 w;
    w.x = tile[j + 0][i]; w.y = tile[j + 1][i]; w.z = tile[j + 2][i]; w.w = tile[j + 3][i];
    *reinterpret_cast<ushort4*>(op + (long)(c0 + i) * ldout + r0 + j) = w;
}

// ---------------------------------------------------------------------------
// Pure-bf16 MFMA GEMM (r9-green): C = scale*A.Bt (+bias, relu), 128x128 tile,
// global_load_lds width-16 staging. Batched via blockIdx.z.
// ---------------------------------------------------------------------------
template<bool BIAS, bool RELU, bool OUTBF16>
__global__ __launch_bounds__(256) void gemm_bt(
    const unsigned short* __restrict__ A, int lda,
    const unsigned short* __restrict__ B, int ldb,
    void* __restrict__ Cv, int ldc,
    const float* __restrict__ bias, float scale, int K, int Hdiv,
    long sAb, long sAh, long sAz,
    long sBb, long sBh, long sBz,
    long sCb, long sCh, long sCz)
{
    const int m0 = blockIdx.y * 128;
    const int n0 = blockIdx.x * 128;
    int z  = blockIdx.z;
    int bb = z / Hdiv, hh = z % Hdiv;
    const unsigned short* Ab = A + bb * sAb + hh * sAh + (long)z * sAz;
    const unsigned short* Bb = B + bb * sBb + hh * sBh + (long)z * sBz;
    long coff = bb * sCb + hh * sCh + (long)z * sCz;

    __shared__ unsigned short As[128 * 32];
    __shared__ unsigned short Bs[128 * 32];

    const int tid  = threadIdx.x;
    const int lane = tid & 63;
    const int wave = tid >> 6;
    const int wm   = (wave >> 1) * 64;
    const int wn   = (wave & 1) * 64;
    const int lm   = lane & 15;
    const int kq   = (lane >> 4) * 8;

    f32x4 acc[4][4] = {};

    for (int k0 = 0; k0 < K; k0 += 32) {
#pragma unroll
        for (int it = 0; it < 2; ++it) {
            int id = tid + it * 256;
            int r  = id >> 2;
            int c8 = (id & 3) * 8;
            const unsigned short* gA = Ab + (long)(m0 + r) * lda + k0 + c8;
            const unsigned short* gB = Bb + (long)(n0 + r) * ldb + k0 + c8;
#if HAS_ASYNC
            unsigned short* lA = &As[(size_t)(it * 256 + wave * 64) * 8];
            unsigned short* lB = &Bs[(size_t)(it * 256 + wave * 64) * 8];
            __builtin_amdgcn_global_load_lds(
                (const __attribute__((address_space(1))) void*)gA,
                (__attribute__((address_space(3))) void*)lA, 16, 0, 0);
            __builtin_amdgcn_global_load_lds(
                (const __attribute__((address_space(1))) void*)gB,
                (__attribute__((address_space(3))) void*)lB, 16, 0, 0);
#else
            *reinterpret_cast<uint4*>(&As[(size_t)id * 8]) =
                *reinterpret_cast<const uint4*>(gA);
            *reinterpret_cast<uint4*>(&Bs[(size_t)id * 8]) =
                *reinterpret_cast<const uint4*>(gB);
#endif
        }
        __syncthreads();

        short8 af[4], bfr[4];
#pragma unroll
        for (int i = 0; i < 4; ++i)
            af[i] = *reinterpret_cast<const short8*>(&As[(wm + i * 16 + lm) * 32 + kq]);
#pragma unroll
        for (int j = 0; j < 4; ++j)
            bfr[j] = *reinterpret_cast<const short8*>(&Bs[(wn + j * 16 + lm) * 32 + kq]);
#pragma unroll
        for (int i = 0; i < 4; ++i)
#pragma unroll
            for (int j = 0; j < 4; ++j)
                acc[i][j] = __builtin_amdgcn_mfma_f32_16x16x32_bf16(af[i], bfr[j], acc[i][j], 0, 0, 0);
        __syncthreads();
    }

#pragma unroll
    for (int j = 0; j < 4; ++j) {
        int col  = n0 + wn + j * 16 + lm;
        float bv = 0.f;
        if (BIAS) bv = bias[col];
#pragma unroll
        for (int i = 0; i < 4; ++i) {
#pragma unroll
            for (int r = 0; r < 4; ++r) {
                int row = m0 + wm + i * 16 + (lane >> 4) * 4 + r;
                float v = acc[i][j][r] * scale + bv;
                if (RELU) v = fmaxf(v, 0.f);
                long idx = coff + (long)row * ldc + col;
                if (OUTBF16) reinterpret_cast<unsigned short*>(Cv)[idx] = f2b(v);
                else         reinterpret_cast<float*>(Cv)[idx] = v;
            }
        }
    }
}

// ---------------------------------------------------------------------------
// Fused flash attention. Grid 8*nbh blocks; balanced XCD-affinity swizzle:
//   x=L&7, m=L>>3, qt=m&7, z=x+8*(m>>3)  (nbh%8==0)
//   -> all q-tiles of a bh share L%8 (XCD) AND qt varies fastest (balance).
// Phase 1: causal staging ([0,(qt+1)*64) K rows) + per-wave MFMA bound NT.
// Phase 2: full 512 keys, V double-buffered (16 KiB halves of Ks), one
//   barrier per iteration; staging overlaps MFMA; Pw is wave-private.
// ---------------------------------------------------------------------------
__global__ __launch_bounds__(256) void flash_attn(
    const unsigned short* __restrict__ Qh,
    const unsigned short* __restrict__ Kh,
    const unsigned short* __restrict__ VhT,
    unsigned short* __restrict__ Vatt,
    const int* __restrict__ maskc, int bh0, float scale, int nbh)
{
    const int tid  = threadIdx.x;
    const int lane = tid & 63;
    const int wave = tid >> 6;
    const int lm   = lane & 15;
    const int qg   = lane >> 4;
    const int kq   = qg * 8;

    const int L = blockIdx.x;
    int z, qt;
    if ((nbh & 7) == 0) {
        int x = L & 7, m = L >> 3;
        qt = m & 7;
        z  = x + 8 * (m >> 3);
    } else {
        z = L % nbh; qt = L / nbh;
    }
    const int b_l = z >> 2, h = z & 3;
    const int m0  = qt * 64;
    const int wq0 = m0 + wave * 16;
    const long qkbase = (long)b_l * SEQ * HD + (long)h * DM;
    const unsigned short* Aq = Qh + qkbase;
    const unsigned short* Ak = Kh + qkbase;
    const unsigned short* Av = VhT + (long)b_l * SEQ * HD + (long)h * SEQ * DM;
    unsigned short* Ov = Vatt + qkbase;
    const int bglob = (bh0 + z) >> 2;

    __shared__ unsigned short Ks[SEQ * 32];                 // 32 KiB
    __shared__ __align__(16) unsigned short Pw[4][16][40];  // 5 KiB

    f32x4 S[32] = {};
    const int NT = (m0 >> 4) + wave + 1;     // causal tile bound (wave-uniform)

    // ---- Phase 1: S = Q.K^T over 8 d-chunks of 32; K rows [0,(qt+1)*64) ----
    for (int kc = 0; kc < 8; ++kc) {
        for (int it = 0; it <= qt; ++it) {
            int id = tid + it * 256;
            const unsigned short* g = Ak + (long)(id >> 2) * HD + kc * 32 + (id & 3) * 8;
#if HAS_ASYNC
            unsigned short* l = &Ks[(size_t)(it * 256 + wave * 64) * 8];
            __builtin_amdgcn_global_load_lds(
                (const __attribute__((address_space(1))) void*)g,
                (__attribute__((address_space(3))) void*)l, 16, 0, 0);
#else
            *reinterpret_cast<uint4*>(&Ks[(size_t)id * 8]) =
                *reinterpret_cast<const uint4*>(g);
#endif
        }
        short8 qf = *reinterpret_cast<const short8*>(
            Aq + (long)(wq0 + lm) * HD + kc * 32 + kq);
        __syncthreads();
#pragma unroll
        for (int nt = 0; nt < 32; ++nt) {
            if (nt < NT) {
                short8 bf = *reinterpret_cast<const short8*>(&Ks[(nt * 16 + lm) * 32 + kq]);
                S[nt] = __builtin_amdgcn_mfma_f32_16x16x32_bf16(qf, bf, S[nt], 0, 0, 0);
            }
        }
        __syncthreads();
    }

    // ---- Prefetch V chunk 0 into Vs buffer 0 (overlaps softmax below) ----
    unsigned short* Vb0 = Ks;            // 16 KiB
    unsigned short* Vb1 = Ks + 8192;     // 16 KiB
#pragma unroll
    for (int it = 0; it < 4; ++it) {
        int id = tid + it * 256;
        const unsigned short* g = Av + (long)(id >> 2) * SEQ + (id & 3) * 8;
#if HAS_ASYNC
        unsigned short* l = &Vb0[(size_t)(it * 256 + wave * 64) * 8];
        __builtin_amdgcn_global_load_lds(
            (const __attribute__((address_space(1))) void*)g,
            (__attribute__((address_space(3))) void*)l, 16, 0, 0);
#else
        *reinterpret_cast<uint4*>(&Vb0[(size_t)id * 8]) =
            *reinterpret_cast<const uint4*>(g);
#endif
    }

    // ---- Softmax in registers (overlaps the V prefetch) ----
    int   qrow[4];
    bool  rowm[4];
    float mx[4], sm[4];
#pragma unroll
    for (int r = 0; r < 4; ++r) {
        int q = wq0 + qg * 4 + r;
        qrow[r] = q;
        rowm[r] = maskc[bglob * SEQ + q] != 0;
        mx[r] = -3.4e38f;
    }
#pragma unroll
    for (int nt = 0; nt < 32; ++nt) {
        int k = nt * 16 + lm;
#pragma unroll
        for (int r = 0; r < 4; ++r) {
            float v = S[nt][r] * scale;
            if (k > qrow[r] || rowm[r]) v = NEGV;
            S[nt][r] = v;
            mx[r] = fmaxf(mx[r], v);
        }
    }
#pragma unroll
    for (int r = 0; r < 4; ++r) {
#pragma unroll
        for (int off = 8; off >= 1; off >>= 1)
            mx[r] = fmaxf(mx[r], __shfl_xor(mx[r], off));
        sm[r] = 0.f;
    }
#pragma unroll
    for (int nt = 0; nt < 32; ++nt)
#pragma unroll
        for (int r = 0; r < 4; ++r) {
            float e = __expf(S[nt][r] - mx[r]);
            S[nt][r] = e;
            sm[r] += e;
        }
#pragma unroll
    for (int r = 0; r < 4; ++r) {
#pragma unroll
        for (int off = 8; off >= 1; off >>= 1)
            sm[r] += __shfl_xor(sm[r], off);
        sm[r] = 1.0f / sm[r];
    }
#pragma unroll
    for (int nt = 0; nt < 32; ++nt)
#pragma unroll
        for (int r = 0; r < 4; ++r) S[nt][r] *= sm[r];

    // ---- Phase 2: O = P.V, 16 key-chunks of 32, double-buffered V ----
    f32x4 O[16] = {};
    for (int kc2 = 0; kc2 < 16; ++kc2) {
        unsigned short* Vcur = (kc2 & 1) ? Vb1 : Vb0;
        __syncthreads();     // drains staging of chunk kc2 (+ prior reads)
        if (kc2 < 15) {      // prefetch chunk kc2+1 into the other buffer
            unsigned short* Vnext = (kc2 & 1) ? Vb0 : Vb1;
#pragma unroll
            for (int it = 0; it < 4; ++it) {
                int id = tid + it * 256;
                const unsigned short* g =
                    Av + (long)(id >> 2) * SEQ + (kc2 + 1) * 32 + (id & 3) * 8;
#if HAS_ASYNC
                unsigned short* l = &Vnext[(size_t)(it * 256 + wave * 64) * 8];
                __builtin_amdgcn_global_load_lds(
                    (const __attribute__((address_space(1))) void*)g,
                    (__attribute__((address_space(3))) void*)l, 16, 0, 0);
#else
                *reinterpret_cast<uint4*>(&Vnext[(size_t)id * 8]) =
                    *reinterpret_cast<const uint4*>(g);
#endif
            }
        }
        // P chunk (32 keys): C-layout regs -> wave-private LDS (A-layout src)
#pragma unroll
        for (int t = 0; t < 2; ++t) {
            int nt = kc2 * 2 + t;
#pragma unroll
            for (int r = 0; r < 4; ++r)
                Pw[wave][qg * 4 + r][t * 16 + lm] = f2b(S[nt][r]);
        }
        short8 pf = *reinterpret_cast<const short8*>(&Pw[wave][lm][kq]);
#pragma unroll
        for (int nt2 = 0; nt2 < 16; ++nt2) {
            short8 vf = *reinterpret_cast<const short8*>(&Vcur[(nt2 * 16 + lm) * 32 + kq]);
            O[nt2] = __builtin_amdgcn_mfma_f32_16x16x32_bf16(pf, vf, O[nt2], 0, 0, 0);
        }
    }

    // ---- epilogue ----
#pragma unroll
    for (int nt2 = 0; nt2 < 16; ++nt2) {
#pragma unroll
        for (int r = 0; r < 4; ++r) {
            int l = wq0 + qg * 4 + r;
            Ov[(long)l * HD + nt2 * 16 + lm] = f2b(O[nt2][r]);
        }
    }
}

// ---------------------------------------------------------------------------
// LN1: x = bf16 AttO + fp32 Q + fp32 pe  ->  fp32 Xf AND bf16 Xb
// ---------------------------------------------------------------------------
__global__ __launch_bounds__(256) void ln1_kernel(
    const unsigned short* __restrict__ AttO, const float* __restrict__ Q,
    const float* __restrict__ pe,
    const float* __restrict__ gamma, const float* __restrict__ beta,
    float* __restrict__ outf, unsigned short* __restrict__ outb)
{
    int row  = blockIdx.x * 4 + (threadIdx.x >> 6);
    int lane = threadIdx.x & 63;
    long base = (long)row * DM + lane * 4;
    ushort4 a = *reinterpret_cast<const ushort4*>(AttO + base);
    float4 qv = *reinterpret_cast<const float4*>(Q + base);
    float4 pv = *reinterpret_cast<const float4*>(pe + (base & PE_MASK));
    float x[4] = {b2f(a.x) + qv.x + pv.x, b2f(a.y) + qv.y + pv.y,
                  b2f(a.z) + qv.z + pv.z, b2f(a.w) + qv.w + pv.w};
    float s = x[0] + x[1] + x[2] + x[3];
#pragma unroll
    for (int off = 32; off > 0; off >>= 1) s += __shfl_xor(s, off);
    float mu = s * (1.0f / DM);
    float vs = 0.f;
#pragma unroll
    for (int t = 0; t < 4; ++t) { float d = x[t] - mu; vs += d * d; }
#pragma unroll
    for (int off = 32; off > 0; off >>= 1) vs += __shfl_xor(vs, off);
    float inv = rsqrtf(vs * (1.0f / DM) + 1e-5f);
    int d0 = lane * 4;
    float4 g = *reinterpret_cast<const float4*>(gamma + d0);
    float4 bt = *reinterpret_cast<const float4*>(beta + d0);
    float4 o;
    o.x = (x[0] - mu) * inv * g.x + bt.x;
    o.y = (x[1] - mu) * inv * g.y + bt.y;
    o.z = (x[2] - mu) * inv * g.z + bt.z;
    o.w = (x[3] - mu) * inv * g.w + bt.w;
    *reinterpret_cast<float4*>(outf + base) = o;
    ushort4 ob;
    ob.x = f2b(o.x); ob.y = f2b(o.y); ob.z = f2b(o.z); ob.w = f2b(o.w);
    *reinterpret_cast<ushort4*>(outb + base) = ob;
}

// ---------------------------------------------------------------------------
// LN2: x = fp32 F + fp32 X  ->  FP32 out
// ---------------------------------------------------------------------------
__global__ __launch_bounds__(256) void ln2_kernel(
    const float* __restrict__ F, const float* __restrict__ X,
    const float* __restrict__ gamma, const float* __restrict__ beta,
    float* __restrict__ out)
{
    int row  = blockIdx.x * 4 + (threadIdx.x >> 6);
    int lane = threadIdx.x & 63;
    long base = (long)row * DM + lane * 4;
    float4 a = *reinterpret_cast<const float4*>(F + base);
    float4 c = *reinterpret_cast<const float4*>(X + base);
    float x[4] = {a.x + c.x, a.y + c.y, a.z + c.z, a.w + c.w};
    float s = x[0] + x[1] + x[2] + x[3];
#pragma unroll
    for (int off = 32; off > 0; off >>= 1) s += __shfl_xor(s, off);
    float mu = s * (1.0f / DM);
    float vs = 0.f;
#pragma unroll
    for (int t = 0; t < 4; ++t) { float d = x[t] - mu; vs += d * d; }
#pragma unroll
    for (int off = 32; off > 0; off >>= 1) vs += __shfl_xor(vs, off);
    float inv = rsqrtf(vs * (1.0f / DM) + 1e-5f);
    int d0 = lane * 4;
    float4 g = *reinterpret_cast<const float4*>(gamma + d0);
    float4 bt = *reinterpret_cast<const float4*>(beta + d0);
    float4 o;
    o.x = (x[0] - mu) * inv * g.x + bt.x;
    o.y = (x[1] - mu) * inv * g.y + bt.y;
    o.z = (x[2] - mu) * inv * g.z + bt.z;
    o.w = (x[3] - mu) * inv * g.w + bt.w;
    *reinterpret_cast<float4*>(out + base) = o;
}

// ---------------------------------------------------------------------------
extern "C" void kernel_launch(void* const* d_in, const int* in_sizes, int n_in,
                              void* d_out, int out_size, void* d_ws, size_t ws_size,
                              hipStream_t stream)
{
    const float* Q  = (const float*)d_in[0];
    const float* Ki = (const float*)d_in[1];
    const float* Vi = (const float*)d_in[2];
    const unsigned char* mask_raw = (const unsigned char*)d_in[3];
    const float* pe = (const float*)d_in[4];
    const float* Wq = (const float*)d_in[5];
    const float* Wk = (const float*)d_in[6];
    const float* Wv = (const float*)d_in[7];
    const float* Wo = (const float*)d_in[8];
    const float* w1 = (const float*)d_in[9];
    const float* b1 = (const float*)d_in[10];
    const float* w2 = (const float*)d_in[11];
    const float* b2 = (const float*)d_in[12];
    const float* gamma = (const float*)d_in[13];
    const float* beta  = (const float*)d_in[14];
    float* out = (float*)d_out;

    const size_t MiB = 1048576;
    char* ws = (char*)d_ws;

    // ---- adaptive chunk size: footprint = 59 + max(5*CB, 24) MiB ----
    int CB = 1;
    for (int cb = 32; cb >= 1; cb >>= 1) {
        size_t scr_sz = (size_t)(5 * cb) * MiB;
        if (scr_sz < 24 * MiB) scr_sz = 24 * MiB;
        if ((59 * MiB + scr_sz) <= ws_size) { CB = cb; break; }
    }
    const int NCH = NB / CB;

    // ---- fixed low regions ----
    unsigned short* WqT  = (unsigned short*)(ws);                 // 512 KiB each
    unsigned short* WkT  = WqT + 262144;
    unsigned short* WvT  = WkT + 262144;
    unsigned short* WoT  = WvT + 262144;
    unsigned short* w1b  = (unsigned short*)(ws + 2 * MiB);       // 128 KiB
    unsigned short* w2b  = w1b + 65536;                           // 128 KiB
    int*            maskc = (int*)(ws + 2 * MiB + 262144);        // 64 KiB
    unsigned short* Qp   = (unsigned short*)(ws + 3 * MiB);       // 8 MiB bf16
    unsigned short* Kp   = (unsigned short*)(ws + 11 * MiB);      // 8 MiB
    unsigned short* Vp   = (unsigned short*)(ws + 19 * MiB);      // 8 MiB
    unsigned short* AttO = (unsigned short*)(ws + 27 * MiB);      // 8 MiB
    unsigned short* Xb   = (unsigned short*)(ws + 35 * MiB);      // 8 MiB
    float*          Xf   = (float*)(ws + 43 * MiB);               // 16 MiB
    char*           scr  = ws + 59 * MiB;
    // chunk scratch (CB MiB each)
    unsigned short* Qh   = (unsigned short*)(scr);
    unsigned short* Kh   = (unsigned short*)(scr + (size_t)CB * MiB);
    unsigned short* Vh   = (unsigned short*)(scr + (size_t)2 * CB * MiB);
    unsigned short* VhT  = (unsigned short*)(scr + (size_t)3 * CB * MiB);
    unsigned short* Vatt = (unsigned short*)(scr + (size_t)4 * CB * MiB);
    // tail aliases over scratch (chunk buffers dead by then)
    unsigned short* H1   = (unsigned short*)(scr);                // 8 MiB bf16
    float*          Ff   = (float*)(scr + 8 * MiB);               // 16 MiB fp32

    const float scale = (float)(1.0 / (16.0 + 1e-6));
    const long CROWS = (long)CB * SEQ;
    const long CBELT = (long)CB * MiB / 2;     // chunk-buffer stride, elements

    // 0. prep (merged): mask, weight transposes/conversions, fused PE-add
    mask_canon<<<64, 256, 0, stream>>>(mask_raw, maskc);
    transpose_f2b3<<<dim3(32, 8, 3), 256, 0, stream>>>(Wq, Wk, Wv, WqT, HD, DM, 262144);
    transpose_f2b<<<dim3(8, 32, 1), 256, 0, stream>>>(Wo, WoT, DM, HD);
    conv2<<<128, 256, 0, stream>>>(w1, w2, w1b, w2b);
    addpe3<<<12288, 256, 0, stream>>>(Q, Ki, Vi, pe, Qp, Kp, Vp);

    // 1. attention in NCH chunks of CB batches
    for (int c = 0; c < NCH; ++c) {
        const long r0   = (long)c * CROWS;
        const int  bh0  = c * CB * NH;
        const int  gy   = (int)(CROWS / 128);
        const int  nbh  = CB * NH;

        // all 3 projections in ONE dispatch (z=0:Q, 1:K, 2:V)
        gemm_bt<false, false, true><<<dim3(8, gy, 3), 256, 0, stream>>>(
            Qp + r0 * DM, DM, WqT, DM, Qh, HD, nullptr, 1.f, DM,
            1, 4194304, 0, 0, 262144, 0, 0, CBELT, 0, 0);

        // per-head V transpose: VhT[bl][h][d][l] = Vh[bl][l][h*256+d]
        transpose_bf16<<<dim3(8, 16, CB * NH), 256, 0, stream>>>(
            Vh, VhT, HD, SEQ, (long)SEQ * HD, DM, (long)SEQ * HD, (long)SEQ * DM, NH);

        // fused attention (balanced XCD swizzle + causal skip + V dbuf)
        flash_attn<<<dim3(8 * nbh, 1, 1), 256, 0, stream>>>(
            Qh, Kh, VhT, Vatt, maskc, bh0, scale, nbh);

        // output projection for this chunk -> AttO rows [r0, r0+CROWS)
        gemm_bt<false, false, true><<<dim3(2, gy, 1), 256, 0, stream>>>(
            Vatt, HD, WoT, HD, AttO + r0 * DM, DM, nullptr, 1.f, HD,
            1, 0,0,0, 0,0,0, 0,0,0);
    }

    // 2. LN1: X = LN(Q + pe + AttO) -> fp32 Xf + bf16 Xb
    ln1_kernel<<<4096, 256, 0, stream>>>(AttO, Q, pe, gamma, beta, Xf, Xb);

    // 3. FFN1: H1 = relu(Xb @ w1^T + b1) -> bf16
    gemm_bt<true, true, true><<<dim3(2, 128, 1), 256, 0, stream>>>(
        Xb, DM, w1b, DM, H1, DM, b1, 1.f, DM, 1, 0,0,0, 0,0,0, 0,0,0);
    // 4. FFN2: F = H1 @ w2^T + b2 -> fp32
    gemm_bt<true, false, false><<<dim3(2, 128, 1), 256, 0, stream>>>(
        H1, DM, w2b, DM, Ff, DM, b2, 1.f, DM, 1, 0,0,0, 0,0,0, 0,0,0);

    // 5. LN2: out = LN(F + X) -> FP32
    ln2_kernel<<<4096, 256, 0, stream>>>(Ff, Xf, gamma, beta, out);
}